// Round 2
// baseline (530.943 us; speedup 1.0000x reference)
//
#include <hip/hip_runtime.h>
#include <hip/hip_bf16.h>

#define B_ 2
#define S_ 2048
#define E_ 1024
#define H_ 16
#define D_ 64
#define M_ 4096  // B_*S_

typedef __bf16 bf16_t;
typedef bf16_t bf16x8 __attribute__((ext_vector_type(8)));
typedef float f32x4 __attribute__((ext_vector_type(4)));

__device__ __forceinline__ f32x4 mfma16(bf16x8 a, bf16x8 b, f32x4 c) {
    return __builtin_amdgcn_mfma_f32_16x16x32_bf16(a, b, c, 0, 0, 0);
}
__device__ __forceinline__ unsigned short f2bf(float f) {
    unsigned int u = __float_as_uint(f);
    unsigned int r = (u + 0x7fffu + ((u >> 16) & 1u)) >> 16;
    return (unsigned short)r;
}
__device__ __forceinline__ float bf2f(unsigned short s) {
    return __uint_as_float(((unsigned int)s) << 16);
}
// order-preserving float<->uint for atomic min/max
__device__ __forceinline__ unsigned int fenc(float x) {
    unsigned int u = __float_as_uint(x);
    return (u & 0x80000000u) ? ~u : (u | 0x80000000u);
}
__device__ __forceinline__ float fdec(unsigned int u) {
    return __uint_as_float((u & 0x80000000u) ? (u ^ 0x80000000u) : ~u);
}

__global__ void k_init(unsigned int* mm) {
    int t = threadIdx.x;
    if (t < 2) { mm[t * 2] = 0xFFFFFFFFu; mm[t * 2 + 1] = 0u; }
}

__global__ __launch_bounds__(256) void k_cast(const float* __restrict__ src,
                                              unsigned short* __restrict__ dst, int n8) {
    int i = blockIdx.x * 256 + threadIdx.x;
    if (i >= n8) return;
    const float4* s4 = (const float4*)src;
    float4 a = s4[2 * i], c = s4[2 * i + 1];
    uint4 o;
    o.x = (unsigned int)f2bf(a.x) | ((unsigned int)f2bf(a.y) << 16);
    o.y = (unsigned int)f2bf(a.z) | ((unsigned int)f2bf(a.w) << 16);
    o.z = (unsigned int)f2bf(c.x) | ((unsigned int)f2bf(c.y) << 16);
    o.w = (unsigned int)f2bf(c.z) | ((unsigned int)f2bf(c.w) << 16);
    ((uint4*)dst)[i] = o;
}

// C[m][n] = sum_k A[m][k]*B[n][k] + bias[n].  A:[4096][1024] bf16, B:[1024][1024] bf16 (row=n, contiguous k).
// MODE 0: write bf16 v in [b][h][s][d] layout + per-batch min/max atomics.
// MODE 1: write fp32 to outf[m][n].
template <int MODE>
__global__ __launch_bounds__(256) void k_gemm(const unsigned short* __restrict__ A,
                                              const unsigned short* __restrict__ Bm,
                                              const float* __restrict__ bias,
                                              unsigned short* __restrict__ outb,
                                              float* __restrict__ outf,
                                              unsigned int* __restrict__ mm) {
    const int K = 1024;
    int tid = threadIdx.x, lane = tid & 63, w = tid >> 6;
    int wm = w >> 1, wn = w & 1;
    int m0 = blockIdx.x * 128 + wm * 64, n0 = blockIdx.y * 128 + wn * 64;
    int lrow = lane & 15, lgrp = lane >> 4;
    f32x4 acc[4][4];
    for (int i = 0; i < 4; ++i)
        for (int j = 0; j < 4; ++j) acc[i][j] = (f32x4){0.f, 0.f, 0.f, 0.f};
    const unsigned short* Ap = A + (size_t)(m0 + lrow) * K + lgrp * 8;
    const unsigned short* Bp = Bm + (size_t)(n0 + lrow) * K + lgrp * 8;
    for (int k = 0; k < K; k += 32) {
        bf16x8 af[4], bfr[4];
#pragma unroll
        for (int t = 0; t < 4; ++t) af[t] = *reinterpret_cast<const bf16x8*>(Ap + (size_t)t * 16 * K + k);
#pragma unroll
        for (int t = 0; t < 4; ++t) bfr[t] = *reinterpret_cast<const bf16x8*>(Bp + (size_t)t * 16 * K + k);
#pragma unroll
        for (int mt = 0; mt < 4; ++mt)
#pragma unroll
            for (int nt = 0; nt < 4; ++nt) acc[mt][nt] = mfma16(af[mt], bfr[nt], acc[mt][nt]);
    }
    float vmin = 1e30f, vmax = -1e30f;
#pragma unroll
    for (int nt = 0; nt < 4; ++nt) {
        float bs = bias[n0 + nt * 16 + lrow];
#pragma unroll
        for (int mt = 0; mt < 4; ++mt)
#pragma unroll
            for (int r = 0; r < 4; ++r) {
                int mrow = m0 + mt * 16 + lgrp * 4 + r;
                int ncol = n0 + nt * 16 + lrow;
                float val = acc[mt][nt][r] + bs;
                if constexpr (MODE == 0) {
                    vmin = fminf(vmin, val);
                    vmax = fmaxf(vmax, val);
                    int b = mrow >> 11, s = mrow & 2047, h = ncol >> 6, d = ncol & 63;
                    outb[(size_t)((b * 16 + h) * 2048 + s) * 64 + d] = f2bf(val);
                } else {
                    outf[(size_t)mrow * 1024 + ncol] = val;
                }
            }
    }
    if constexpr (MODE == 0) {
#pragma unroll
        for (int m = 1; m < 64; m <<= 1) {
            vmin = fminf(vmin, __shfl_xor(vmin, m));
            vmax = fmaxf(vmax, __shfl_xor(vmax, m));
        }
        if (lane == 0) {
            int b = m0 >> 11;
            atomicMin(&mm[b * 2], fenc(vmin));
            atomicMax(&mm[b * 2 + 1], fenc(vmax));
        }
    }
}

// v_bf [bh][s][64] -> vt [bh][64][s], 64x64 tiles via LDS
__global__ __launch_bounds__(256) void k_transpose(const unsigned short* __restrict__ vbuf,
                                                   unsigned short* __restrict__ vt) {
    __shared__ __align__(16) unsigned short tile[64][72];
    int bh = blockIdx.y, st = blockIdx.x;
    int t = threadIdx.x;
    int row = t >> 2, cb = (t & 3) * 16;
    const unsigned short* src = vbuf + (size_t)bh * S_ * 64 + (size_t)st * 64 * 64;
    *(uint4*)&tile[row][cb] = *(const uint4*)(src + row * 64 + cb);
    *(uint4*)&tile[row][cb + 8] = *(const uint4*)(src + row * 64 + cb + 8);
    __syncthreads();
    int d = row, sb = cb;
    unsigned short tmp[16];
#pragma unroll
    for (int i = 0; i < 16; ++i) tmp[i] = tile[sb + i][d];
    unsigned short* dst = vt + (size_t)bh * 64 * S_ + (size_t)d * S_ + st * 64 + sb;
    *(uint4*)dst = *(uint4*)&tmp[0];
    *(uint4*)(dst + 8) = *(uint4*)&tmp[8];
}

// per (b,h): lane=d, serial prefix scan over s; inv = 1/((prefix_mean(v)-vmin)*ir + 0.5)
__global__ void k_scan(const unsigned short* __restrict__ vb, float* __restrict__ inv,
                       const unsigned int* __restrict__ mm) {
    int bh = blockIdx.x;
    int lane = threadIdx.x;
    int b = bh >> 4;
    float vmin = fdec(mm[b * 2]), vmax = fdec(mm[b * 2 + 1]);
    float ir = 1.0f / (vmax - vmin + 1e-8f);
    const unsigned short* src = vb + (size_t)bh * S_ * 64 + lane;
    float* dst = inv + (size_t)bh * S_ * 64 + lane;
    float acc = 0.f;
#pragma unroll 8
    for (int s = 0; s < S_; ++s) {
        acc += bf2f(src[(size_t)s * 64]);
        float phi = acc / (float)(s + 1);
        float den = (phi - vmin) * ir + 0.5f;
        dst[(size_t)s * 64] = 1.0f / den;
    }
}

// gene' = inv / rowsum(inv) * ir   (inv_range folded in; min-shift cancels in softmax)
__global__ __launch_bounds__(256) void k_rowsum(const float* __restrict__ invd,
                                                unsigned short* __restrict__ gene,
                                                const unsigned int* __restrict__ mm) {
    int row = blockIdx.x * 4 + (threadIdx.x >> 6);
    int lane = threadIdx.x & 63;
    int b = row >> 15;
    float vmin = fdec(mm[b * 2]), vmax = fdec(mm[b * 2 + 1]);
    float ir = 1.0f / (vmax - vmin + 1e-8f);
    float xv = invd[(size_t)row * 64 + lane];
    float s = xv;
#pragma unroll
    for (int m = 1; m < 64; m <<= 1) s += __shfl_xor(s, m);
    gene[(size_t)row * 64 + lane] = f2bf(xv / s * ir);
}

// Fixed-max flash attention.
// Scores s = v_j . gene'_i ; true org = s - vmin*ir in [0,1]  (gene rows sum to 1, v_scaled in [0,1]).
// So p = exp(s - (vmin*ir + 1)) in [~e^-2, ~e^0.1]: no running max, no rescale, plain sums.
// 1 wave = 16 query rows; key tile = 64; P through XOR-swizzled per-wave LDS.
__global__ __launch_bounds__(256) void k_attn(const unsigned short* __restrict__ gene,
                                              const unsigned short* __restrict__ vb,
                                              const unsigned short* __restrict__ vt,
                                              unsigned short* __restrict__ attn_out,
                                              const unsigned int* __restrict__ mm) {
    __shared__ __align__(16) unsigned short plds[4][16 * 80];  // 16 rows x 80 shorts (10 chunks of 8)
    int tid = threadIdx.x;
    int w = tid >> 6, lane = tid & 63;
    int bh = blockIdx.y;
    int it = 127 - (blockIdx.x * 4 + w);  // reversed: longest waves dispatch first
    int i0 = it * 16;
    int lrow = lane & 15, lgrp = lane >> 4;

    int b = bh >> 4;
    float vmin = fdec(mm[b * 2]), vmax = fdec(mm[b * 2 + 1]);
    float ir = 1.0f / (vmax - vmin + 1e-8f);
    float C = vmin * ir + 1.0f;  // fixed softmax shift

    const unsigned short* gbase = gene + (size_t)bh * S_ * 64;
    const unsigned short* vbase = vb + (size_t)bh * S_ * 64;
    const unsigned short* tbase = vt + (size_t)bh * 64 * S_;

    bf16x8 ga0 = *reinterpret_cast<const bf16x8*>(gbase + (size_t)(i0 + lrow) * 64 + lgrp * 8);
    bf16x8 ga1 = *reinterpret_cast<const bf16x8*>(gbase + (size_t)(i0 + lrow) * 64 + 32 + lgrp * 8);

    f32x4 acc[4];
#pragma unroll
    for (int n = 0; n < 4; ++n) acc[n] = (f32x4){0.f, 0.f, 0.f, 0.f};
    float lsum[4] = {0.f, 0.f, 0.f, 0.f};

    unsigned short* pl = &plds[w][0];
    int njt = (i0 >> 6) + 1;
    for (int jt = 0; jt < njt; ++jt) {
        int j0 = jt << 6;
        // ---- scores: 16 queries x 64 keys ----
        f32x4 Sv[4];
#pragma unroll
        for (int n = 0; n < 4; ++n) {
            const unsigned short* vr = vbase + (size_t)(j0 + n * 16 + lrow) * 64 + lgrp * 8;
            bf16x8 b0 = *reinterpret_cast<const bf16x8*>(vr);
            bf16x8 b1 = *reinterpret_cast<const bf16x8*>(vr + 32);
            f32x4 c = (f32x4){0.f, 0.f, 0.f, 0.f};
            c = mfma16(ga0, b0, c);
            c = mfma16(ga1, b1, c);
            Sv[n] = c;
        }
        // ---- p = exp(s - C); accumulate denominator; write P (XOR-swizzled chunks) ----
        bool tail = (j0 + 63 > i0);  // only the last tile straddles the diagonal
        if (tail) {
#pragma unroll
            for (int n = 0; n < 4; ++n)
#pragma unroll
                for (int r = 0; r < 4; ++r) {
                    int ii = i0 + lgrp * 4 + r;
                    int jj = j0 + n * 16 + lrow;
                    float p = (jj <= ii) ? __expf(Sv[n][r] - C) : 0.f;
                    lsum[r] += p;
                    int row = lgrp * 4 + r;
                    int cw = (2 * n + (lrow >> 3)) ^ (row & 7);
                    pl[row * 80 + cw * 8 + (lrow & 7)] = f2bf(p);
                }
        } else {
#pragma unroll
            for (int n = 0; n < 4; ++n)
#pragma unroll
                for (int r = 0; r < 4; ++r) {
                    float p = __expf(Sv[n][r] - C);
                    lsum[r] += p;
                    int row = lgrp * 4 + r;
                    int cw = (2 * n + (lrow >> 3)) ^ (row & 7);
                    pl[row * 80 + cw * 8 + (lrow & 7)] = f2bf(p);
                }
        }
        // wave-local LDS RAW: DS ops in-order per wave; compiler inserts lgkmcnt.
        bf16x8 pa0 = *reinterpret_cast<const bf16x8*>(pl + lrow * 80 + ((lgrp ^ (lrow & 7)) << 3));
        bf16x8 pa1 = *reinterpret_cast<const bf16x8*>(pl + lrow * 80 + (((4 + lgrp) ^ (lrow & 7)) << 3));
        // ---- PV: acc[n] += P(16x64) * vt_chunk(64 keys x 64 d) ----
#pragma unroll
        for (int n = 0; n < 4; ++n) {
            const unsigned short* tb = tbase + (size_t)(n * 16 + lrow) * S_ + j0 + lgrp * 8;
            bf16x8 t0 = *reinterpret_cast<const bf16x8*>(tb);
            bf16x8 t1 = *reinterpret_cast<const bf16x8*>(tb + 32);
            acc[n] = mfma16(pa0, t0, acc[n]);
            acc[n] = mfma16(pa1, t1, acc[n]);
        }
    }
    // one-time denominator reduce across the 16 key-lanes (preserves lgrp row groups)
#pragma unroll
    for (int r = 0; r < 4; ++r) {
#pragma unroll
        for (int m = 1; m < 16; m <<= 1) lsum[r] += __shfl_xor(lsum[r], m);
        lsum[r] = 1.0f / lsum[r];
    }
    int bb = bh >> 4, h = bh & 15;
#pragma unroll
    for (int n = 0; n < 4; ++n)
#pragma unroll
        for (int r = 0; r < 4; ++r) {
            int ii = i0 + lgrp * 4 + r;
            int e = h * 64 + n * 16 + lrow;
            attn_out[(size_t)(bb * S_ + ii) * E_ + e] = f2bf(acc[n][r] * lsum[r]);
        }
}

extern "C" void kernel_launch(void* const* d_in, const int* in_sizes, int n_in,
                              void* d_out, int out_size, void* d_ws, size_t ws_size,
                              hipStream_t stream) {
    const float* x = (const float*)d_in[0];
    const float* wv_w = (const float*)d_in[1];
    const float* wv_b = (const float*)d_in[2];
    const float* wo_w = (const float*)d_in[3];
    const float* wo_b = (const float*)d_in[4];
    float* out = (float*)d_out;

    char* w = (char*)d_ws;
    unsigned short* x_bf = (unsigned short*)(w);               // 8 MB
    unsigned short* wv_bf = (unsigned short*)(w + 8388608);    // 2 MB
    unsigned short* wo_bf = (unsigned short*)(w + 10485760);   // 2 MB
    unsigned short* v_bf = (unsigned short*)(w + 12582912);    // 8 MB  [b][h][s][d]
    unsigned short* vt_bf = (unsigned short*)(w + 20971520);   // 8 MB  [b][h][d][s]
    float* invd = (float*)(w + 29360128);                      // 16 MB
    unsigned short* gene = (unsigned short*)(w + 46137344);    // 8 MB
    unsigned short* a_bf = (unsigned short*)(w + 54525952);    // 8 MB  [b][s][e]
    unsigned int* mm = (unsigned int*)(w + 62914560);          // 16 B
    if (ws_size < 62914576) return;  // insufficient workspace -> fail loudly

    k_init<<<1, 64, 0, stream>>>(mm);
    k_cast<<<2048, 256, 0, stream>>>(x, x_bf, 524288);
    k_cast<<<512, 256, 0, stream>>>(wv_w, wv_bf, 131072);
    k_cast<<<512, 256, 0, stream>>>(wo_w, wo_bf, 131072);
    k_gemm<0><<<dim3(32, 8), 256, 0, stream>>>(x_bf, wv_bf, wv_b, v_bf, nullptr, mm);
    k_transpose<<<dim3(32, 32), 256, 0, stream>>>(v_bf, vt_bf);
    k_scan<<<32, 64, 0, stream>>>(v_bf, invd, mm);
    k_rowsum<<<16384, 256, 0, stream>>>(invd, gene, mm);
    k_attn<<<dim3(32, 32), 256, 0, stream>>>(gene, v_bf, vt_bf, a_bf, mm);
    k_gemm<1><<<dim3(32, 8), 256, 0, stream>>>(a_bf, wo_bf, wo_b, nullptr, out, nullptr);
}

// Round 3
// 421.729 us; speedup vs baseline: 1.2590x; 1.2590x over previous
//
#include <hip/hip_runtime.h>
#include <hip/hip_bf16.h>

#define B_ 2
#define S_ 2048
#define E_ 1024
#define H_ 16
#define D_ 64
#define M_ 4096  // B_*S_

typedef __bf16 bf16_t;
typedef bf16_t bf16x8 __attribute__((ext_vector_type(8)));
typedef float f32x4 __attribute__((ext_vector_type(4)));

__device__ __forceinline__ f32x4 mfma16(bf16x8 a, bf16x8 b, f32x4 c) {
    return __builtin_amdgcn_mfma_f32_16x16x32_bf16(a, b, c, 0, 0, 0);
}
__device__ __forceinline__ unsigned short f2bf(float f) {
    unsigned int u = __float_as_uint(f);
    unsigned int r = (u + 0x7fffu + ((u >> 16) & 1u)) >> 16;
    return (unsigned short)r;
}
__device__ __forceinline__ float bf2f(unsigned short s) {
    return __uint_as_float(((unsigned int)s) << 16);
}
// order-preserving float<->uint for atomic min/max
__device__ __forceinline__ unsigned int fenc(float x) {
    unsigned int u = __float_as_uint(x);
    return (u & 0x80000000u) ? ~u : (u | 0x80000000u);
}
__device__ __forceinline__ float fdec(unsigned int u) {
    return __uint_as_float((u & 0x80000000u) ? (u ^ 0x80000000u) : ~u);
}

__global__ void k_init(unsigned int* mm) {
    int t = threadIdx.x;
    if (t < 2) { mm[t * 2] = 0xFFFFFFFFu; mm[t * 2 + 1] = 0u; }
}

__global__ __launch_bounds__(256) void k_cast(const float* __restrict__ src,
                                              unsigned short* __restrict__ dst, int n8) {
    int i = blockIdx.x * 256 + threadIdx.x;
    if (i >= n8) return;
    const float4* s4 = (const float4*)src;
    float4 a = s4[2 * i], c = s4[2 * i + 1];
    uint4 o;
    o.x = (unsigned int)f2bf(a.x) | ((unsigned int)f2bf(a.y) << 16);
    o.y = (unsigned int)f2bf(a.z) | ((unsigned int)f2bf(a.w) << 16);
    o.z = (unsigned int)f2bf(c.x) | ((unsigned int)f2bf(c.y) << 16);
    o.w = (unsigned int)f2bf(c.z) | ((unsigned int)f2bf(c.w) << 16);
    ((uint4*)dst)[i] = o;
}

// C[m][n] = sum_k A[m][k]*B[n][k] + bias[n].  A:[4096][1024], B:[1024][1024] (row=n, contiguous k), bf16.
// Tile 128(m) x 64(n), BK=64, double-buffered LDS (padded rows: 72 shorts = 144B -> conflict-free b128).
// MODE 0: write bf16 v in [b][h][s][d] layout + per-batch min/max atomics.  MODE 1: fp32 outf[m][n].
template <int MODE>
__global__ __launch_bounds__(256, 2) void k_gemm(const unsigned short* __restrict__ A,
                                                 const unsigned short* __restrict__ Bm,
                                                 const float* __restrict__ bias,
                                                 unsigned short* __restrict__ outb,
                                                 float* __restrict__ outf,
                                                 unsigned int* __restrict__ mm) {
    __shared__ __align__(16) unsigned short Asm[2][128][72];
    __shared__ __align__(16) unsigned short Bsm[2][64][72];
    const int K = 1024;
    int tid = threadIdx.x, lane = tid & 63, w = tid >> 6;
    int wm = w >> 1, wn = w & 1;
    int m0 = blockIdx.x * 128, n0 = blockIdx.y * 64;
    int lrow = lane & 15, lgrp = lane >> 4;
    // staging maps: A tile 128x64 shorts (2 thr/row, 32-short halves); B tile 64x64 (4 thr/row, 16-short quarters)
    int ar = tid >> 1, ac = (tid & 1) * 32;
    int br = tid >> 2, bc = (tid & 3) * 16;
    const unsigned short* Ast = A + (size_t)(m0 + ar) * K + ac;
    const unsigned short* Bst = Bm + (size_t)(n0 + br) * K + bc;
    f32x4 acc[4][2];
#pragma unroll
    for (int i = 0; i < 4; ++i)
#pragma unroll
        for (int j = 0; j < 2; ++j) acc[i][j] = (f32x4){0.f, 0.f, 0.f, 0.f};
    // prologue: stage k-step 0 into buffer 0
    {
        uint4 a0 = *(const uint4*)(Ast);
        uint4 a1 = *(const uint4*)(Ast + 8);
        uint4 a2 = *(const uint4*)(Ast + 16);
        uint4 a3 = *(const uint4*)(Ast + 24);
        uint4 b0 = *(const uint4*)(Bst);
        uint4 b1 = *(const uint4*)(Bst + 8);
        *(uint4*)&Asm[0][ar][ac] = a0;
        *(uint4*)&Asm[0][ar][ac + 8] = a1;
        *(uint4*)&Asm[0][ar][ac + 16] = a2;
        *(uint4*)&Asm[0][ar][ac + 24] = a3;
        *(uint4*)&Bsm[0][br][bc] = b0;
        *(uint4*)&Bsm[0][br][bc + 8] = b1;
    }
    __syncthreads();
    for (int ks = 0; ks < 16; ++ks) {
        int cur = ks & 1;
        bool pf = (ks < 15);
        uint4 ra0, ra1, ra2, ra3, rb0, rb1;
        if (pf) {
            int k1 = (ks + 1) * 64;
            ra0 = *(const uint4*)(Ast + k1);
            ra1 = *(const uint4*)(Ast + k1 + 8);
            ra2 = *(const uint4*)(Ast + k1 + 16);
            ra3 = *(const uint4*)(Ast + k1 + 24);
            rb0 = *(const uint4*)(Bst + k1);
            rb1 = *(const uint4*)(Bst + k1 + 8);
        }
#pragma unroll
        for (int kh = 0; kh < 2; ++kh) {
            bf16x8 af[4], bfr[2];
#pragma unroll
            for (int mt = 0; mt < 4; ++mt)
                af[mt] = *(const bf16x8*)&Asm[cur][wm * 64 + mt * 16 + lrow][kh * 32 + lgrp * 8];
#pragma unroll
            for (int nt = 0; nt < 2; ++nt)
                bfr[nt] = *(const bf16x8*)&Bsm[cur][wn * 32 + nt * 16 + lrow][kh * 32 + lgrp * 8];
#pragma unroll
            for (int mt = 0; mt < 4; ++mt)
#pragma unroll
                for (int nt = 0; nt < 2; ++nt) acc[mt][nt] = mfma16(af[mt], bfr[nt], acc[mt][nt]);
        }
        __syncthreads();
        if (pf) {
            int nb = cur ^ 1;
            *(uint4*)&Asm[nb][ar][ac] = ra0;
            *(uint4*)&Asm[nb][ar][ac + 8] = ra1;
            *(uint4*)&Asm[nb][ar][ac + 16] = ra2;
            *(uint4*)&Asm[nb][ar][ac + 24] = ra3;
            *(uint4*)&Bsm[nb][br][bc] = rb0;
            *(uint4*)&Bsm[nb][br][bc + 8] = rb1;
        }
        __syncthreads();
    }
    float vmin = 1e30f, vmax = -1e30f;
#pragma unroll
    for (int nt = 0; nt < 2; ++nt) {
        int ncol = n0 + wn * 32 + nt * 16 + lrow;
        float bs = bias[ncol];
#pragma unroll
        for (int mt = 0; mt < 4; ++mt)
#pragma unroll
            for (int r = 0; r < 4; ++r) {
                int mrow = m0 + wm * 64 + mt * 16 + lgrp * 4 + r;
                float val = acc[mt][nt][r] + bs;
                if constexpr (MODE == 0) {
                    vmin = fminf(vmin, val);
                    vmax = fmaxf(vmax, val);
                    int b = mrow >> 11, s = mrow & 2047, h = ncol >> 6, d = ncol & 63;
                    outb[(size_t)((b * 16 + h) * 2048 + s) * 64 + d] = f2bf(val);
                } else {
                    outf[(size_t)mrow * 1024 + ncol] = val;
                }
            }
    }
    if constexpr (MODE == 0) {
#pragma unroll
        for (int m = 1; m < 64; m <<= 1) {
            vmin = fminf(vmin, __shfl_xor(vmin, m));
            vmax = fmaxf(vmax, __shfl_xor(vmax, m));
        }
        if (lane == 0) {
            int b = m0 >> 11;
            atomicMin(&mm[b * 2], fenc(vmin));
            atomicMax(&mm[b * 2 + 1], fenc(vmax));
        }
    }
}

// v_bf [bh][s][64] -> vt [bh][64][s], 64x64 tiles via LDS
__global__ __launch_bounds__(256) void k_transpose(const unsigned short* __restrict__ vbuf,
                                                   unsigned short* __restrict__ vt) {
    __shared__ __align__(16) unsigned short tile[64][72];
    int bh = blockIdx.y, st = blockIdx.x;
    int t = threadIdx.x;
    int row = t >> 2, cb = (t & 3) * 16;
    const unsigned short* src = vbuf + (size_t)bh * S_ * 64 + (size_t)st * 64 * 64;
    *(uint4*)&tile[row][cb] = *(const uint4*)(src + row * 64 + cb);
    *(uint4*)&tile[row][cb + 8] = *(const uint4*)(src + row * 64 + cb + 8);
    __syncthreads();
    int d = row, sb = cb;
    unsigned short tmp[16];
#pragma unroll
    for (int i = 0; i < 16; ++i) tmp[i] = tile[sb + i][d];
    unsigned short* dst = vt + (size_t)bh * 64 * S_ + (size_t)d * S_ + st * 64 + sb;
    *(uint4*)dst = *(uint4*)&tmp[0];
    *(uint4*)(dst + 8) = *(uint4*)&tmp[8];
}

// per (b,h): lane=d; 4 waves split s into quarters: parallel base reduction + 512-step serial scan.
__global__ void k_scan(const unsigned short* __restrict__ vb, float* __restrict__ inv,
                       const unsigned int* __restrict__ mm) {
    int bh = blockIdx.x;
    int w = threadIdx.x >> 6, d = threadIdx.x & 63;
    int b = bh >> 4;
    float vmin = fdec(mm[b * 2]), vmax = fdec(mm[b * 2 + 1]);
    float ir = __fdividef(1.0f, vmax - vmin + 1e-8f);
    const unsigned short* src = vb + (size_t)bh * S_ * 64 + d;
    float* dst = inv + (size_t)bh * S_ * 64 + d;
    int s0 = w * 512;
    float a0 = 0.f, a1 = 0.f, a2 = 0.f, a3 = 0.f;
    for (int s = 0; s < s0; s += 4) {
        a0 += bf2f(src[(size_t)s * 64]);
        a1 += bf2f(src[(size_t)(s + 1) * 64]);
        a2 += bf2f(src[(size_t)(s + 2) * 64]);
        a3 += bf2f(src[(size_t)(s + 3) * 64]);
    }
    float acc = (a0 + a1) + (a2 + a3);
    for (int s = s0; s < s0 + 512; ++s) {
        acc += bf2f(src[(size_t)s * 64]);
        float phi = __fdividef(acc, (float)(s + 1));
        float den = (phi - vmin) * ir + 0.5f;
        dst[(size_t)s * 64] = __fdividef(1.0f, den);
    }
}

// gene' = inv / rowsum(inv) * ir   (inv_range folded in; min-shift cancels in softmax)
__global__ __launch_bounds__(256) void k_rowsum(const float* __restrict__ invd,
                                                unsigned short* __restrict__ gene,
                                                const unsigned int* __restrict__ mm) {
    int row = blockIdx.x * 4 + (threadIdx.x >> 6);
    int lane = threadIdx.x & 63;
    int b = row >> 15;
    float vmin = fdec(mm[b * 2]), vmax = fdec(mm[b * 2 + 1]);
    float ir = __fdividef(1.0f, vmax - vmin + 1e-8f);
    float xv = invd[(size_t)row * 64 + lane];
    float s = xv;
#pragma unroll
    for (int m = 1; m < 64; m <<= 1) s += __shfl_xor(s, m);
    gene[(size_t)row * 64 + lane] = f2bf(__fdividef(xv, s) * ir);
}

// Fixed-max flash attention, block-cooperative staged tiles.
// Block = 4 waves covering 64 consecutive query rows of one bh; key tile = 64.
// v-tile + vt-tile double-buffered in padded LDS (reg-staged: issue-early / write-late).
// p = exp(s - (vmin*ir + 1)) in [~e^-2, ~e^0.1]: fixed shift, plain sums, one reduce at end.
__global__ __launch_bounds__(256, 3) void k_attn(const unsigned short* __restrict__ gene,
                                                 const unsigned short* __restrict__ vb,
                                                 const unsigned short* __restrict__ vt,
                                                 unsigned short* __restrict__ attn_out,
                                                 const unsigned int* __restrict__ mm) {
    __shared__ __align__(16) unsigned short v_lds[2][64][72];  // [buf][j-local][d] (+pad)
    __shared__ __align__(16) unsigned short t_lds[2][64][72];  // [buf][d][j-local] (+pad)
    __shared__ __align__(16) unsigned short plds[4][16 * 72];  // per-wave P tile
    int tid = threadIdx.x;
    int w = tid >> 6, lane = tid & 63;
    // XCD-aware decode: each XCD owns 4 bh; qt reversed (long blocks first)
    int bid = blockIdx.x;
    int xcd = bid & 7, slot = bid >> 3;
    int bh = xcd * 4 + (slot >> 5);
    int qt = 31 - (slot & 31);
    int i0 = qt * 64 + w * 16;
    int lrow = lane & 15, lgrp = lane >> 4;

    int b = bh >> 4;
    float vmin = fdec(mm[b * 2]), vmax = fdec(mm[b * 2 + 1]);
    float ir = __fdividef(1.0f, vmax - vmin + 1e-8f);
    float C = vmin * ir + 1.0f;  // fixed softmax shift

    const unsigned short* gbase = gene + (size_t)bh * S_ * 64;
    const unsigned short* vbase = vb + (size_t)bh * S_ * 64;
    const unsigned short* tbase = vt + (size_t)bh * 64 * S_;

    // per-thread staging pointers (64 rows x 4 col-chunks of 16 shorts)
    int srow = tid >> 2, scol = (tid & 3) * 16;
    const unsigned short* vstage = vbase + (size_t)srow * 64 + scol;   // advance j0*64 per tile
    const unsigned short* tstage = tbase + (size_t)srow * S_ + scol;   // advance j0 per tile

    bf16x8 ga0 = *(const bf16x8*)(gbase + (size_t)(i0 + lrow) * 64 + lgrp * 8);
    bf16x8 ga1 = *(const bf16x8*)(gbase + (size_t)(i0 + lrow) * 64 + 32 + lgrp * 8);

    f32x4 acc[4];
#pragma unroll
    for (int n = 0; n < 4; ++n) acc[n] = (f32x4){0.f, 0.f, 0.f, 0.f};
    float lsum[4] = {0.f, 0.f, 0.f, 0.f};
    unsigned short* pl = &plds[w][0];
    int njt = qt + 1;

    // prologue: stage tile 0 into buffer 0
    {
        uint4 a0 = *(const uint4*)(vstage);
        uint4 a1 = *(const uint4*)(vstage + 8);
        uint4 b0 = *(const uint4*)(tstage);
        uint4 b1 = *(const uint4*)(tstage + 8);
        *(uint4*)&v_lds[0][srow][scol] = a0;
        *(uint4*)&v_lds[0][srow][scol + 8] = a1;
        *(uint4*)&t_lds[0][srow][scol] = b0;
        *(uint4*)&t_lds[0][srow][scol + 8] = b1;
    }
    __syncthreads();

    for (int jt = 0; jt < njt; ++jt) {
        int cur = jt & 1;
        bool pf = (jt + 1 < njt);
        uint4 pa_, pb_, pc_, pd_;
        if (pf) {  // issue next-tile loads early; write after barrier (latency hides under compute)
            const unsigned short* vs = vstage + (size_t)(jt + 1) * 4096;
            const unsigned short* ts = tstage + (size_t)(jt + 1) * 64;
            pa_ = *(const uint4*)(vs);
            pb_ = *(const uint4*)(vs + 8);
            pc_ = *(const uint4*)(ts);
            pd_ = *(const uint4*)(ts + 8);
        }
        int j0 = jt << 6;
        // ---- scores: 16 queries x 64 keys ----
        f32x4 Sv[4];
#pragma unroll
        for (int n = 0; n < 4; ++n) {
            const unsigned short* vr = &v_lds[cur][n * 16 + lrow][lgrp * 8];
            bf16x8 b0 = *(const bf16x8*)(vr);
            bf16x8 b1 = *(const bf16x8*)(vr + 32);
            f32x4 c = (f32x4){0.f, 0.f, 0.f, 0.f};
            c = mfma16(ga0, b0, c);
            c = mfma16(ga1, b1, c);
            Sv[n] = c;
        }
        bool tail = (jt == qt);
#pragma unroll
        for (int n = 0; n < 4; ++n)
#pragma unroll
            for (int r = 0; r < 4; ++r) {
                float p = __expf(Sv[n][r] - C);
                if (tail) {
                    int ii = i0 + lgrp * 4 + r;
                    int jj = j0 + n * 16 + lrow;
                    p = (jj <= ii) ? p : 0.f;
                }
                lsum[r] += p;
                pl[(lgrp * 4 + r) * 72 + n * 16 + lrow] =
                    (unsigned short)((__float_as_uint(p) + 0x8000u) >> 16);
            }
        // wave-local LDS RAW: DS ops in-order per wave; compiler inserts lgkmcnt.
        bf16x8 pa0 = *(const bf16x8*)(pl + lrow * 72 + lgrp * 8);
        bf16x8 pa1 = *(const bf16x8*)(pl + lrow * 72 + 32 + lgrp * 8);
        // ---- PV: acc[n] += P(16x64) * vt(64 d x 64 keys) ----
#pragma unroll
        for (int n = 0; n < 4; ++n) {
            const unsigned short* tr = &t_lds[cur][n * 16 + lrow][lgrp * 8];
            bf16x8 t0 = *(const bf16x8*)(tr);
            bf16x8 t1 = *(const bf16x8*)(tr + 32);
            acc[n] = mfma16(pa0, t0, acc[n]);
            acc[n] = mfma16(pa1, t1, acc[n]);
        }
        __syncthreads();
        if (pf) {
            int nb = cur ^ 1;
            *(uint4*)&v_lds[nb][srow][scol] = pa_;
            *(uint4*)&v_lds[nb][srow][scol + 8] = pb_;
            *(uint4*)&t_lds[nb][srow][scol] = pc_;
            *(uint4*)&t_lds[nb][srow][scol + 8] = pd_;
        }
        __syncthreads();
    }
    // one-time denominator reduce across the 16 key-lanes (preserves lgrp row groups)
#pragma unroll
    for (int r = 0; r < 4; ++r) {
#pragma unroll
        for (int m = 1; m < 16; m <<= 1) lsum[r] += __shfl_xor(lsum[r], m);
        lsum[r] = __fdividef(1.0f, lsum[r]);
    }
    int bb = bh >> 4, h = bh & 15;
#pragma unroll
    for (int n = 0; n < 4; ++n)
#pragma unroll
        for (int r = 0; r < 4; ++r) {
            int ii = i0 + lgrp * 4 + r;
            int e = h * 64 + n * 16 + lrow;
            attn_out[(size_t)(bb * S_ + ii) * E_ + e] = f2bf(acc[n][r] * lsum[r]);
        }
}

extern "C" void kernel_launch(void* const* d_in, const int* in_sizes, int n_in,
                              void* d_out, int out_size, void* d_ws, size_t ws_size,
                              hipStream_t stream) {
    const float* x = (const float*)d_in[0];
    const float* wv_w = (const float*)d_in[1];
    const float* wv_b = (const float*)d_in[2];
    const float* wo_w = (const float*)d_in[3];
    const float* wo_b = (const float*)d_in[4];
    float* out = (float*)d_out;

    char* w = (char*)d_ws;
    unsigned short* x_bf = (unsigned short*)(w);               // 8 MB
    unsigned short* wv_bf = (unsigned short*)(w + 8388608);    // 2 MB
    unsigned short* wo_bf = (unsigned short*)(w + 10485760);   // 2 MB
    unsigned short* v_bf = (unsigned short*)(w + 12582912);    // 8 MB  [b][h][s][d]
    unsigned short* vt_bf = (unsigned short*)(w + 20971520);   // 8 MB  [b][h][d][s]
    float* invd = (float*)(w + 29360128);                      // 16 MB
    unsigned short* gene = (unsigned short*)(w + 46137344);    // 8 MB
    unsigned short* a_bf = (unsigned short*)(w + 54525952);    // 8 MB  [b][s][e]
    unsigned int* mm = (unsigned int*)(w + 62914560);          // 16 B
    if (ws_size < 62914576) return;  // insufficient workspace -> fail loudly

    k_init<<<1, 64, 0, stream>>>(mm);
    k_cast<<<2048, 256, 0, stream>>>(x, x_bf, 524288);
    k_cast<<<512, 256, 0, stream>>>(wv_w, wv_bf, 131072);
    k_cast<<<512, 256, 0, stream>>>(wo_w, wo_bf, 131072);
    k_gemm<0><<<dim3(32, 16), 256, 0, stream>>>(x_bf, wv_bf, wv_b, v_bf, nullptr, mm);
    k_transpose<<<dim3(32, 32), 256, 0, stream>>>(v_bf, vt_bf);
    k_scan<<<32, 256, 0, stream>>>(v_bf, invd, mm);
    k_rowsum<<<16384, 256, 0, stream>>>(invd, gene, mm);
    k_attn<<<1024, 256, 0, stream>>>(gene, v_bf, vt_bf, a_bf, mm);
    k_gemm<1><<<dim3(32, 16), 256, 0, stream>>>(a_bf, wo_bf, wo_b, nullptr, out, nullptr);
}

// Round 4
// 178.726 us; speedup vs baseline: 2.9707x; 2.3596x over previous
//
#include <hip/hip_runtime.h>
#include <hip/hip_bf16.h>

#define B_ 2
#define S_ 2048
#define E_ 1024
#define H_ 16
#define D_ 64
#define M_ 4096  // B_*S_

typedef __bf16 bf16_t;
typedef bf16_t bf16x8 __attribute__((ext_vector_type(8)));
typedef float f32x4 __attribute__((ext_vector_type(4)));

__device__ __forceinline__ f32x4 mfma16(bf16x8 a, bf16x8 b, f32x4 c) {
    return __builtin_amdgcn_mfma_f32_16x16x32_bf16(a, b, c, 0, 0, 0);
}
__device__ __forceinline__ unsigned short f2bf(float f) {
    unsigned int u = __float_as_uint(f);
    unsigned int r = (u + 0x7fffu + ((u >> 16) & 1u)) >> 16;
    return (unsigned short)r;
}
__device__ __forceinline__ float bf2f(unsigned short s) {
    return __uint_as_float(((unsigned int)s) << 16);
}
// order-preserving float<->uint for atomic min/max
__device__ __forceinline__ unsigned int fenc(float x) {
    unsigned int u = __float_as_uint(x);
    return (u & 0x80000000u) ? ~u : (u | 0x80000000u);
}
__device__ __forceinline__ float fdec(unsigned int u) {
    return __uint_as_float((u & 0x80000000u) ? (u ^ 0x80000000u) : ~u);
}

__global__ void k_init(unsigned int* mm) {
    int t = threadIdx.x;
    if (t < 2) { mm[t * 2] = 0xFFFFFFFFu; mm[t * 2 + 1] = 0u; }
}

__global__ __launch_bounds__(256) void k_cast(const float* __restrict__ src,
                                              unsigned short* __restrict__ dst, int n8) {
    int i = blockIdx.x * 256 + threadIdx.x;
    if (i >= n8) return;
    const float4* s4 = (const float4*)src;
    float4 a = s4[2 * i], c = s4[2 * i + 1];
    uint4 o;
    o.x = (unsigned int)f2bf(a.x) | ((unsigned int)f2bf(a.y) << 16);
    o.y = (unsigned int)f2bf(a.z) | ((unsigned int)f2bf(a.w) << 16);
    o.z = (unsigned int)f2bf(c.x) | ((unsigned int)f2bf(c.y) << 16);
    o.w = (unsigned int)f2bf(c.z) | ((unsigned int)f2bf(c.w) << 16);
    ((uint4*)dst)[i] = o;
}

// C[m][n] = sum_k A[m][k]*B[n][k] + bias[n].  A:[4096][1024], B:[1024][1024] (row=n, contiguous k), bf16.
// Tile 128(m) x 64(n), BK=64, double-buffered LDS (padded rows: 72 shorts = 144B -> conflict-free b128).
// MODE 0: write bf16 v in [b][h][s][d] layout + per-batch min/max atomics.  MODE 1: fp32 outf[m][n].
template <int MODE>
__global__ __launch_bounds__(256, 2) void k_gemm(const unsigned short* __restrict__ A,
                                                 const unsigned short* __restrict__ Bm,
                                                 const float* __restrict__ bias,
                                                 unsigned short* __restrict__ outb,
                                                 float* __restrict__ outf,
                                                 unsigned int* __restrict__ mm) {
    __shared__ __align__(16) unsigned short Asm[2][128][72];
    __shared__ __align__(16) unsigned short Bsm[2][64][72];
    const int K = 1024;
    int tid = threadIdx.x, lane = tid & 63, w = tid >> 6;
    int wm = w >> 1, wn = w & 1;
    int m0 = blockIdx.x * 128, n0 = blockIdx.y * 64;
    int lrow = lane & 15, lgrp = lane >> 4;
    // staging maps: A tile 128x64 shorts (2 thr/row, 32-short halves); B tile 64x64 (4 thr/row, 16-short quarters)
    int ar = tid >> 1, ac = (tid & 1) * 32;
    int br = tid >> 2, bc = (tid & 3) * 16;
    const unsigned short* Ast = A + (size_t)(m0 + ar) * K + ac;
    const unsigned short* Bst = Bm + (size_t)(n0 + br) * K + bc;
    f32x4 acc[4][2];
#pragma unroll
    for (int i = 0; i < 4; ++i)
#pragma unroll
        for (int j = 0; j < 2; ++j) acc[i][j] = (f32x4){0.f, 0.f, 0.f, 0.f};
    // prologue: stage k-step 0 into buffer 0
    {
        uint4 a0 = *(const uint4*)(Ast);
        uint4 a1 = *(const uint4*)(Ast + 8);
        uint4 a2 = *(const uint4*)(Ast + 16);
        uint4 a3 = *(const uint4*)(Ast + 24);
        uint4 b0 = *(const uint4*)(Bst);
        uint4 b1 = *(const uint4*)(Bst + 8);
        *(uint4*)&Asm[0][ar][ac] = a0;
        *(uint4*)&Asm[0][ar][ac + 8] = a1;
        *(uint4*)&Asm[0][ar][ac + 16] = a2;
        *(uint4*)&Asm[0][ar][ac + 24] = a3;
        *(uint4*)&Bsm[0][br][bc] = b0;
        *(uint4*)&Bsm[0][br][bc + 8] = b1;
    }
    __syncthreads();
    for (int ks = 0; ks < 16; ++ks) {
        int cur = ks & 1;
        bool pf = (ks < 15);
        uint4 ra0, ra1, ra2, ra3, rb0, rb1;
        if (pf) {
            int k1 = (ks + 1) * 64;
            ra0 = *(const uint4*)(Ast + k1);
            ra1 = *(const uint4*)(Ast + k1 + 8);
            ra2 = *(const uint4*)(Ast + k1 + 16);
            ra3 = *(const uint4*)(Ast + k1 + 24);
            rb0 = *(const uint4*)(Bst + k1);
            rb1 = *(const uint4*)(Bst + k1 + 8);
        }
#pragma unroll
        for (int kh = 0; kh < 2; ++kh) {
            bf16x8 af[4], bfr[2];
#pragma unroll
            for (int mt = 0; mt < 4; ++mt)
                af[mt] = *(const bf16x8*)&Asm[cur][wm * 64 + mt * 16 + lrow][kh * 32 + lgrp * 8];
#pragma unroll
            for (int nt = 0; nt < 2; ++nt)
                bfr[nt] = *(const bf16x8*)&Bsm[cur][wn * 32 + nt * 16 + lrow][kh * 32 + lgrp * 8];
#pragma unroll
            for (int mt = 0; mt < 4; ++mt)
#pragma unroll
                for (int nt = 0; nt < 2; ++nt) acc[mt][nt] = mfma16(af[mt], bfr[nt], acc[mt][nt]);
        }
        __syncthreads();
        if (pf) {
            int nb = cur ^ 1;
            *(uint4*)&Asm[nb][ar][ac] = ra0;
            *(uint4*)&Asm[nb][ar][ac + 8] = ra1;
            *(uint4*)&Asm[nb][ar][ac + 16] = ra2;
            *(uint4*)&Asm[nb][ar][ac + 24] = ra3;
            *(uint4*)&Bsm[nb][br][bc] = rb0;
            *(uint4*)&Bsm[nb][br][bc + 8] = rb1;
        }
        __syncthreads();
    }
    float vmin = 1e30f, vmax = -1e30f;
#pragma unroll
    for (int nt = 0; nt < 2; ++nt) {
        int ncol = n0 + wn * 32 + nt * 16 + lrow;
        float bs = bias[ncol];
#pragma unroll
        for (int mt = 0; mt < 4; ++mt)
#pragma unroll
            for (int r = 0; r < 4; ++r) {
                int mrow = m0 + wm * 64 + mt * 16 + lgrp * 4 + r;
                float val = acc[mt][nt][r] + bs;
                if constexpr (MODE == 0) {
                    vmin = fminf(vmin, val);
                    vmax = fmaxf(vmax, val);
                    int b = mrow >> 11, s = mrow & 2047, h = ncol >> 6, d = ncol & 63;
                    outb[(size_t)((b * 16 + h) * 2048 + s) * 64 + d] = f2bf(val);
                } else {
                    outf[(size_t)mrow * 1024 + ncol] = val;
                }
            }
    }
    if constexpr (MODE == 0) {
#pragma unroll
        for (int m = 1; m < 64; m <<= 1) {
            vmin = fminf(vmin, __shfl_xor(vmin, m));
            vmax = fmaxf(vmax, __shfl_xor(vmax, m));
        }
        if (lane == 0) {
            int b = m0 >> 11;
            atomicMin(&mm[b * 2], fenc(vmin));
            atomicMax(&mm[b * 2 + 1], fenc(vmax));
        }
    }
}

// v_bf [bh][s][64] -> vt [bh][64][s], 64x64 tiles via LDS
__global__ __launch_bounds__(256) void k_transpose(const unsigned short* __restrict__ vbuf,
                                                   unsigned short* __restrict__ vt) {
    __shared__ __align__(16) unsigned short tile[64][72];
    int bh = blockIdx.y, st = blockIdx.x;
    int t = threadIdx.x;
    int row = t >> 2, cb = (t & 3) * 16;
    const unsigned short* src = vbuf + (size_t)bh * S_ * 64 + (size_t)st * 64 * 64;
    *(uint4*)&tile[row][cb] = *(const uint4*)(src + row * 64 + cb);
    *(uint4*)&tile[row][cb + 8] = *(const uint4*)(src + row * 64 + cb + 8);
    __syncthreads();
    int d = row, sb = cb;
    unsigned short tmp[16];
#pragma unroll
    for (int i = 0; i < 16; ++i) tmp[i] = tile[sb + i][d];
    unsigned short* dst = vt + (size_t)bh * 64 * S_ + (size_t)d * S_ + st * 64 + sb;
    *(uint4*)dst = *(uint4*)&tmp[0];
    *(uint4*)(dst + 8) = *(uint4*)&tmp[8];
}

// ---- hierarchical prefix scan over s (2048 chains of length 2048) ----
// pass 1: one wave per (bh, 32-row chunk); lane=d sums its 32 values -> ps[bh][c][d]
__global__ __launch_bounds__(256) void k_scan1(const unsigned short* __restrict__ vb,
                                               float* __restrict__ ps) {
    int g = blockIdx.x * 4 + (threadIdx.x >> 6);
    int d = threadIdx.x & 63;
    int bh = g >> 6, c = g & 63;
    const unsigned short* src = vb + (size_t)bh * S_ * 64 + (size_t)c * 32 * 64 + d;
    float a0 = 0.f, a1 = 0.f, a2 = 0.f, a3 = 0.f;
#pragma unroll
    for (int i = 0; i < 32; i += 4) {
        a0 += bf2f(src[(size_t)i * 64]);
        a1 += bf2f(src[(size_t)(i + 1) * 64]);
        a2 += bf2f(src[(size_t)(i + 2) * 64]);
        a3 += bf2f(src[(size_t)(i + 3) * 64]);
    }
    ps[(size_t)g * 64 + d] = (a0 + a1) + (a2 + a3);
}

// pass 2: one thread per (bh,d); register scan of 64 chunk sums -> exclusive base[bh][c][d]
__global__ __launch_bounds__(64) void k_scan2(const float* __restrict__ ps,
                                              float* __restrict__ base) {
    int bh = blockIdx.x;
    int d = threadIdx.x;
    const float* p = ps + (size_t)bh * 64 * 64 + d;
    float* bo = base + (size_t)bh * 64 * 64 + d;
    float vals[64];
#pragma unroll
    for (int c = 0; c < 64; ++c) vals[c] = p[(size_t)c * 64];
    float run = 0.f;
#pragma unroll
    for (int c = 0; c < 64; ++c) {
        float t = vals[c];
        vals[c] = run;
        run += t;
    }
#pragma unroll
    for (int c = 0; c < 64; ++c) bo[(size_t)c * 64] = vals[c];
}

// pass 3: one wave per (bh, chunk); resume scan from base, fuse rowsum -> gene directly.
// gene = inv / rowsum(inv) * ir  (inv_range folded in; min-shift cancels in softmax)
__global__ __launch_bounds__(256) void k_scan3(const unsigned short* __restrict__ vb,
                                               const float* __restrict__ base,
                                               unsigned short* __restrict__ gene,
                                               const unsigned int* __restrict__ mm) {
    int g = blockIdx.x * 4 + (threadIdx.x >> 6);
    int d = threadIdx.x & 63;
    int bh = g >> 6, c = g & 63;
    int b = bh >> 4;
    float vmin = fdec(mm[b * 2]), vmax = fdec(mm[b * 2 + 1]);
    float ir = __fdividef(1.0f, vmax - vmin + 1e-8f);
    const unsigned short* src = vb + (size_t)bh * S_ * 64 + (size_t)c * 32 * 64 + d;
    unsigned short* dst = gene + (size_t)bh * S_ * 64 + (size_t)c * 32 * 64 + d;
    float acc = base[(size_t)g * 64 + d];
#pragma unroll 4
    for (int i = 0; i < 32; ++i) {
        int s = c * 32 + i;
        acc += bf2f(src[(size_t)i * 64]);
        float phi = __fdividef(acc, (float)(s + 1));
        float inv = __fdividef(1.0f, (phi - vmin) * ir + 0.5f);
        float rs = inv;
#pragma unroll
        for (int m = 1; m < 64; m <<= 1) rs += __shfl_xor(rs, m);
        dst[(size_t)i * 64] = f2bf(__fdividef(inv, rs) * ir);
    }
}

// Fixed-max flash attention, block-cooperative staged tiles.
// Block = 4 waves covering 64 consecutive query rows of one bh; key tile = 64.
// v-tile + vt-tile double-buffered in padded LDS (reg-staged: issue-early / write-late).
// p = exp(s - (vmin*ir + 1)) in [~e^-2, ~e^0.1]: fixed shift, plain sums, one reduce at end.
__global__ __launch_bounds__(256, 3) void k_attn(const unsigned short* __restrict__ gene,
                                                 const unsigned short* __restrict__ vb,
                                                 const unsigned short* __restrict__ vt,
                                                 unsigned short* __restrict__ attn_out,
                                                 const unsigned int* __restrict__ mm) {
    __shared__ __align__(16) unsigned short v_lds[2][64][72];  // [buf][j-local][d] (+pad)
    __shared__ __align__(16) unsigned short t_lds[2][64][72];  // [buf][d][j-local] (+pad)
    __shared__ __align__(16) unsigned short plds[4][16 * 72];  // per-wave P tile
    int tid = threadIdx.x;
    int w = tid >> 6, lane = tid & 63;
    // XCD-aware decode: each XCD owns 4 bh; qt reversed (long blocks first)
    int bid = blockIdx.x;
    int xcd = bid & 7, slot = bid >> 3;
    int bh = xcd * 4 + (slot >> 5);
    int qt = 31 - (slot & 31);
    int i0 = qt * 64 + w * 16;
    int lrow = lane & 15, lgrp = lane >> 4;

    int b = bh >> 4;
    float vmin = fdec(mm[b * 2]), vmax = fdec(mm[b * 2 + 1]);
    float ir = __fdividef(1.0f, vmax - vmin + 1e-8f);
    float C = vmin * ir + 1.0f;  // fixed softmax shift

    const unsigned short* gbase = gene + (size_t)bh * S_ * 64;
    const unsigned short* vbase = vb + (size_t)bh * S_ * 64;
    const unsigned short* tbase = vt + (size_t)bh * 64 * S_;

    // per-thread staging pointers (64 rows x 4 col-chunks of 16 shorts)
    int srow = tid >> 2, scol = (tid & 3) * 16;
    const unsigned short* vstage = vbase + (size_t)srow * 64 + scol;   // advance j0*64 per tile
    const unsigned short* tstage = tbase + (size_t)srow * S_ + scol;   // advance j0 per tile

    bf16x8 ga0 = *(const bf16x8*)(gbase + (size_t)(i0 + lrow) * 64 + lgrp * 8);
    bf16x8 ga1 = *(const bf16x8*)(gbase + (size_t)(i0 + lrow) * 64 + 32 + lgrp * 8);

    f32x4 acc[4];
#pragma unroll
    for (int n = 0; n < 4; ++n) acc[n] = (f32x4){0.f, 0.f, 0.f, 0.f};
    float lsum[4] = {0.f, 0.f, 0.f, 0.f};
    unsigned short* pl = &plds[w][0];
    int njt = qt + 1;

    // prologue: stage tile 0 into buffer 0
    {
        uint4 a0 = *(const uint4*)(vstage);
        uint4 a1 = *(const uint4*)(vstage + 8);
        uint4 b0 = *(const uint4*)(tstage);
        uint4 b1 = *(const uint4*)(tstage + 8);
        *(uint4*)&v_lds[0][srow][scol] = a0;
        *(uint4*)&v_lds[0][srow][scol + 8] = a1;
        *(uint4*)&t_lds[0][srow][scol] = b0;
        *(uint4*)&t_lds[0][srow][scol + 8] = b1;
    }
    __syncthreads();

    for (int jt = 0; jt < njt; ++jt) {
        int cur = jt & 1;
        bool pf = (jt + 1 < njt);
        uint4 pa_, pb_, pc_, pd_;
        if (pf) {  // issue next-tile loads early; write after barrier (latency hides under compute)
            const unsigned short* vs = vstage + (size_t)(jt + 1) * 4096;
            const unsigned short* ts = tstage + (size_t)(jt + 1) * 64;
            pa_ = *(const uint4*)(vs);
            pb_ = *(const uint4*)(vs + 8);
            pc_ = *(const uint4*)(ts);
            pd_ = *(const uint4*)(ts + 8);
        }
        int j0 = jt << 6;
        // ---- scores: 16 queries x 64 keys ----
        f32x4 Sv[4];
#pragma unroll
        for (int n = 0; n < 4; ++n) {
            const unsigned short* vr = &v_lds[cur][n * 16 + lrow][lgrp * 8];
            bf16x8 b0 = *(const bf16x8*)(vr);
            bf16x8 b1 = *(const bf16x8*)(vr + 32);
            f32x4 c = (f32x4){0.f, 0.f, 0.f, 0.f};
            c = mfma16(ga0, b0, c);
            c = mfma16(ga1, b1, c);
            Sv[n] = c;
        }
        bool tail = (jt == qt);
#pragma unroll
        for (int n = 0; n < 4; ++n)
#pragma unroll
            for (int r = 0; r < 4; ++r) {
                float p = __expf(Sv[n][r] - C);
                if (tail) {
                    int ii = i0 + lgrp * 4 + r;
                    int jj = j0 + n * 16 + lrow;
                    p = (jj <= ii) ? p : 0.f;
                }
                lsum[r] += p;
                pl[(lgrp * 4 + r) * 72 + n * 16 + lrow] =
                    (unsigned short)((__float_as_uint(p) + 0x8000u) >> 16);
            }
        // wave-local LDS RAW: DS ops in-order per wave; compiler inserts lgkmcnt.
        bf16x8 pa0 = *(const bf16x8*)(pl + lrow * 72 + lgrp * 8);
        bf16x8 pa1 = *(const bf16x8*)(pl + lrow * 72 + 32 + lgrp * 8);
        // ---- PV: acc[n] += P(16x64) * vt(64 d x 64 keys) ----
#pragma unroll
        for (int n = 0; n < 4; ++n) {
            const unsigned short* tr = &t_lds[cur][n * 16 + lrow][lgrp * 8];
            bf16x8 t0 = *(const bf16x8*)(tr);
            bf16x8 t1 = *(const bf16x8*)(tr + 32);
            acc[n] = mfma16(pa0, t0, acc[n]);
            acc[n] = mfma16(pa1, t1, acc[n]);
        }
        __syncthreads();
        if (pf) {
            int nb = cur ^ 1;
            *(uint4*)&v_lds[nb][srow][scol] = pa_;
            *(uint4*)&v_lds[nb][srow][scol + 8] = pb_;
            *(uint4*)&t_lds[nb][srow][scol] = pc_;
            *(uint4*)&t_lds[nb][srow][scol + 8] = pd_;
        }
        __syncthreads();
    }
    // one-time denominator reduce across the 16 key-lanes (preserves lgrp row groups)
#pragma unroll
    for (int r = 0; r < 4; ++r) {
#pragma unroll
        for (int m = 1; m < 16; m <<= 1) lsum[r] += __shfl_xor(lsum[r], m);
        lsum[r] = __fdividef(1.0f, lsum[r]);
    }
    int bb = bh >> 4, h = bh & 15;
#pragma unroll
    for (int n = 0; n < 4; ++n)
#pragma unroll
        for (int r = 0; r < 4; ++r) {
            int ii = i0 + lgrp * 4 + r;
            int e = h * 64 + n * 16 + lrow;
            attn_out[(size_t)(bb * S_ + ii) * E_ + e] = f2bf(acc[n][r] * lsum[r]);
        }
}

extern "C" void kernel_launch(void* const* d_in, const int* in_sizes, int n_in,
                              void* d_out, int out_size, void* d_ws, size_t ws_size,
                              hipStream_t stream) {
    const float* x = (const float*)d_in[0];
    const float* wv_w = (const float*)d_in[1];
    const float* wv_b = (const float*)d_in[2];
    const float* wo_w = (const float*)d_in[3];
    const float* wo_b = (const float*)d_in[4];
    float* out = (float*)d_out;

    char* w = (char*)d_ws;
    unsigned short* x_bf = (unsigned short*)(w);               // 8 MB
    unsigned short* wv_bf = (unsigned short*)(w + 8388608);    // 2 MB
    unsigned short* wo_bf = (unsigned short*)(w + 10485760);   // 2 MB
    unsigned short* v_bf = (unsigned short*)(w + 12582912);    // 8 MB  [b][h][s][d]
    unsigned short* vt_bf = (unsigned short*)(w + 20971520);   // 8 MB  [b][h][d][s]
    float* ps = (float*)(w + 29360128);                        // 512 KB [bh][c][d]
    float* base = (float*)(w + 29884416);                      // 512 KB [bh][c][d]
    unsigned short* gene = (unsigned short*)(w + 46137344);    // 8 MB
    unsigned short* a_bf = (unsigned short*)(w + 54525952);    // 8 MB  [b][s][e]
    unsigned int* mm = (unsigned int*)(w + 62914560);          // 16 B
    if (ws_size < 62914576) return;  // insufficient workspace -> fail loudly

    k_init<<<1, 64, 0, stream>>>(mm);
    k_cast<<<2048, 256, 0, stream>>>(x, x_bf, 524288);
    k_cast<<<512, 256, 0, stream>>>(wv_w, wv_bf, 131072);
    k_cast<<<512, 256, 0, stream>>>(wo_w, wo_bf, 131072);
    k_gemm<0><<<dim3(32, 16), 256, 0, stream>>>(x_bf, wv_bf, wv_b, v_bf, nullptr, mm);
    k_transpose<<<dim3(32, 32), 256, 0, stream>>>(v_bf, vt_bf);
    k_scan1<<<512, 256, 0, stream>>>(v_bf, ps);
    k_scan2<<<32, 64, 0, stream>>>(ps, base);
    k_scan3<<<512, 256, 0, stream>>>(v_bf, base, gene, mm);
    k_attn<<<1024, 256, 0, stream>>>(gene, v_bf, vt_bf, a_bf, mm);
    k_gemm<1><<<dim3(32, 16), 256, 0, stream>>>(a_bf, wo_bf, wo_b, nullptr, out, nullptr);
}

// Round 5
// 177.515 us; speedup vs baseline: 2.9910x; 1.0068x over previous
//
#include <hip/hip_runtime.h>
#include <hip/hip_bf16.h>

#define B_ 2
#define S_ 2048
#define E_ 1024
#define H_ 16
#define D_ 64
#define M_ 4096  // B_*S_

typedef __bf16 bf16_t;
typedef bf16_t bf16x8 __attribute__((ext_vector_type(8)));
typedef float f32x4 __attribute__((ext_vector_type(4)));
typedef unsigned int u32;

__device__ __forceinline__ f32x4 mfma16(bf16x8 a, bf16x8 b, f32x4 c) {
    return __builtin_amdgcn_mfma_f32_16x16x32_bf16(a, b, c, 0, 0, 0);
}
__device__ __forceinline__ unsigned short f2bf(float f) {
    unsigned int u = __float_as_uint(f);
    unsigned int r = (u + 0x7fffu + ((u >> 16) & 1u)) >> 16;
    return (unsigned short)r;
}
__device__ __forceinline__ float bf2f(unsigned short s) {
    return __uint_as_float(((unsigned int)s) << 16);
}
// order-preserving float<->uint for atomic min/max
__device__ __forceinline__ unsigned int fenc(float x) {
    unsigned int u = __float_as_uint(x);
    return (u & 0x80000000u) ? ~u : (u | 0x80000000u);
}
__device__ __forceinline__ float fdec(unsigned int u) {
    return __uint_as_float((u & 0x80000000u) ? (u ^ 0x80000000u) : ~u);
}
// async global->LDS DMA, 16B per lane; LDS dest = wave-uniform base + lane*16
__device__ __forceinline__ void gload16(const void* g, void* l) {
    __builtin_amdgcn_global_load_lds((const __attribute__((address_space(1))) u32*)g,
                                     (__attribute__((address_space(3))) u32*)l, 16, 0, 0);
}

__global__ void k_init(unsigned int* mm) {
    int t = threadIdx.x;
    if (t < 2) { mm[t * 2] = 0xFFFFFFFFu; mm[t * 2 + 1] = 0u; }
}

__global__ __launch_bounds__(256) void k_cast(const float* __restrict__ src,
                                              unsigned short* __restrict__ dst, int n8) {
    int i = blockIdx.x * 256 + threadIdx.x;
    if (i >= n8) return;
    const float4* s4 = (const float4*)src;
    float4 a = s4[2 * i], c = s4[2 * i + 1];
    uint4 o;
    o.x = (unsigned int)f2bf(a.x) | ((unsigned int)f2bf(a.y) << 16);
    o.y = (unsigned int)f2bf(a.z) | ((unsigned int)f2bf(a.w) << 16);
    o.z = (unsigned int)f2bf(c.x) | ((unsigned int)f2bf(c.y) << 16);
    o.w = (unsigned int)f2bf(c.z) | ((unsigned int)f2bf(c.w) << 16);
    ((uint4*)dst)[i] = o;
}

// C[m][n] = sum_k A[m][k]*B[n][k] + bias[n].  A:[4096][1024], B:[1024][1024] (row=n, contiguous k), bf16.
// m97-style: 128(m) x 64(n) tile, BK=64, global_load_lds(16B) into linear double-buffered LDS,
// one barrier per K-step. Bank conflicts: pre-swizzled GLOBAL source (chunk ^= row&7) + same XOR
// on ds_read addresses; LDS writes stay linear (rule: both-sides-or-neither).
// MODE 0: write bf16 v in [b][h][s][d] layout + per-batch min/max atomics.  MODE 1: fp32 outf[m][n].
template <int MODE>
__global__ __launch_bounds__(256, 3) void k_gemm(const unsigned short* __restrict__ A,
                                                 const unsigned short* __restrict__ Bm,
                                                 const float* __restrict__ bias,
                                                 unsigned short* __restrict__ outb,
                                                 float* __restrict__ outf,
                                                 unsigned int* __restrict__ mm) {
    __shared__ __align__(16) unsigned short Asm[2][8192];  // [buf][128 rows x 64 shorts]
    __shared__ __align__(16) unsigned short Bsm[2][4096];  // [buf][64 rows x 64 shorts]
    const int K = 1024;
    int tid = threadIdx.x, lane = tid & 63, wv = tid >> 6;
    int wm = wv >> 1, wn = wv & 1;
    int m0 = blockIdx.x * 128, n0 = blockIdx.y * 64;
    int lrow = lane & 15, lgrp = lane >> 4, sw = lane & 7;
    int r8 = lane >> 3, ch = lane & 7;
    // pre-swizzled global sources: lane covers (row = i*32 + wv*8 + r8, 16B chunk = ch ^ r8)
    const unsigned short* Ag = A + (size_t)(m0 + wv * 8 + r8) * K + ((ch ^ r8) << 3);
    const unsigned short* Bg = Bm + (size_t)(n0 + wv * 8 + r8) * K + ((ch ^ r8) << 3);
    unsigned short* A0 = &Asm[0][0];
    unsigned short* A1 = &Asm[1][0];
    unsigned short* B0 = &Bsm[0][0];
    unsigned short* B1 = &Bsm[1][0];

#define STAGE(AB, BB, kk)                                                     \
    {                                                                         \
        _Pragma("unroll") for (int i = 0; i < 4; ++i)                         \
            gload16(Ag + (size_t)i * 32 * K + (kk), AB + i * 2048 + wv * 512);\
        _Pragma("unroll") for (int i = 0; i < 2; ++i)                         \
            gload16(Bg + (size_t)i * 32 * K + (kk), BB + i * 2048 + wv * 512);\
    }
#define COMPUTE(AB, BB)                                                           \
    {                                                                             \
        _Pragma("unroll") for (int kh = 0; kh < 2; ++kh) {                        \
            bf16x8 af[4], bfr[2];                                                 \
            _Pragma("unroll") for (int mt = 0; mt < 4; ++mt)                      \
                af[mt] = *(const bf16x8*)(AB + (wm * 64 + mt * 16 + lrow) * 64 +  \
                                          ((((kh << 2) | lgrp) ^ sw) << 3));      \
            _Pragma("unroll") for (int nt = 0; nt < 2; ++nt)                      \
                bfr[nt] = *(const bf16x8*)(BB + (wn * 32 + nt * 16 + lrow) * 64 + \
                                           ((((kh << 2) | lgrp) ^ sw) << 3));     \
            _Pragma("unroll") for (int mt = 0; mt < 4; ++mt)                      \
                _Pragma("unroll") for (int nt = 0; nt < 2; ++nt)                  \
                    acc[mt][nt] = mfma16(af[mt], bfr[nt], acc[mt][nt]);           \
        }                                                                         \
    }

    f32x4 acc[4][2];
#pragma unroll
    for (int i = 0; i < 4; ++i)
#pragma unroll
        for (int j = 0; j < 2; ++j) acc[i][j] = (f32x4){0.f, 0.f, 0.f, 0.f};

    STAGE(A0, B0, 0);
    __syncthreads();
    for (int t = 0; t < 8; ++t) {
        STAGE(A1, B1, (2 * t + 1) * 64);  // stage next while computing cur
        COMPUTE(A0, B0);
        __syncthreads();
        if (t < 7) STAGE(A0, B0, (2 * t + 2) * 64);
        COMPUTE(A1, B1);
        __syncthreads();
    }
#undef STAGE
#undef COMPUTE

    float vmin = 1e30f, vmax = -1e30f;
#pragma unroll
    for (int nt = 0; nt < 2; ++nt) {
        int ncol = n0 + wn * 32 + nt * 16 + lrow;
        float bs = bias[ncol];
#pragma unroll
        for (int mt = 0; mt < 4; ++mt)
#pragma unroll
            for (int r = 0; r < 4; ++r) {
                int mrow = m0 + wm * 64 + mt * 16 + lgrp * 4 + r;
                float val = acc[mt][nt][r] + bs;
                if constexpr (MODE == 0) {
                    vmin = fminf(vmin, val);
                    vmax = fmaxf(vmax, val);
                    int b = mrow >> 11, s = mrow & 2047, h = ncol >> 6, d = ncol & 63;
                    outb[(size_t)((b * 16 + h) * 2048 + s) * 64 + d] = f2bf(val);
                } else {
                    outf[(size_t)mrow * 1024 + ncol] = val;
                }
            }
    }
    if constexpr (MODE == 0) {
#pragma unroll
        for (int m = 1; m < 64; m <<= 1) {
            vmin = fminf(vmin, __shfl_xor(vmin, m));
            vmax = fmaxf(vmax, __shfl_xor(vmax, m));
        }
        if (lane == 0) {
            int b = m0 >> 11;
            atomicMin(&mm[b * 2], fenc(vmin));
            atomicMax(&mm[b * 2 + 1], fenc(vmax));
        }
    }
}

// v_bf [bh][s][64] -> vt [bh][64][s], 64x64 tiles via LDS
__global__ __launch_bounds__(256) void k_transpose(const unsigned short* __restrict__ vbuf,
                                                   unsigned short* __restrict__ vt) {
    __shared__ __align__(16) unsigned short tile[64][72];
    int bh = blockIdx.y, st = blockIdx.x;
    int t = threadIdx.x;
    int row = t >> 2, cb = (t & 3) * 16;
    const unsigned short* src = vbuf + (size_t)bh * S_ * 64 + (size_t)st * 64 * 64;
    *(uint4*)&tile[row][cb] = *(const uint4*)(src + row * 64 + cb);
    *(uint4*)&tile[row][cb + 8] = *(const uint4*)(src + row * 64 + cb + 8);
    __syncthreads();
    int d = row, sb = cb;
    unsigned short tmp[16];
#pragma unroll
    for (int i = 0; i < 16; ++i) tmp[i] = tile[sb + i][d];
    unsigned short* dst = vt + (size_t)bh * 64 * S_ + (size_t)d * S_ + st * 64 + sb;
    *(uint4*)dst = *(uint4*)&tmp[0];
    *(uint4*)(dst + 8) = *(uint4*)&tmp[8];
}

// ---- hierarchical prefix scan over s (2048 chains of length 2048) ----
// pass 1: one wave per (bh, 32-row chunk); lane=d sums its 32 values -> ps[bh][c][d]
__global__ __launch_bounds__(256) void k_scan1(const unsigned short* __restrict__ vb,
                                               float* __restrict__ ps) {
    int g = blockIdx.x * 4 + (threadIdx.x >> 6);
    int d = threadIdx.x & 63;
    int bh = g >> 6, c = g & 63;
    const unsigned short* src = vb + (size_t)bh * S_ * 64 + (size_t)c * 32 * 64 + d;
    float a0 = 0.f, a1 = 0.f, a2 = 0.f, a3 = 0.f;
#pragma unroll
    for (int i = 0; i < 32; i += 4) {
        a0 += bf2f(src[(size_t)i * 64]);
        a1 += bf2f(src[(size_t)(i + 1) * 64]);
        a2 += bf2f(src[(size_t)(i + 2) * 64]);
        a3 += bf2f(src[(size_t)(i + 3) * 64]);
    }
    ps[(size_t)g * 64 + d] = (a0 + a1) + (a2 + a3);
}

// pass 2: one thread per (bh,d); register scan of 64 chunk sums -> exclusive base[bh][c][d]
__global__ __launch_bounds__(64) void k_scan2(const float* __restrict__ ps,
                                              float* __restrict__ base) {
    int bh = blockIdx.x;
    int d = threadIdx.x;
    const float* p = ps + (size_t)bh * 64 * 64 + d;
    float* bo = base + (size_t)bh * 64 * 64 + d;
    float vals[64];
#pragma unroll
    for (int c = 0; c < 64; ++c) vals[c] = p[(size_t)c * 64];
    float run = 0.f;
#pragma unroll
    for (int c = 0; c < 64; ++c) {
        float t = vals[c];
        vals[c] = run;
        run += t;
    }
#pragma unroll
    for (int c = 0; c < 64; ++c) bo[(size_t)c * 64] = vals[c];
}

// pass 3: one wave per (bh, chunk); resume scan from base, fuse rowsum -> gene directly.
// gene = inv / rowsum(inv) * ir  (inv_range folded in; min-shift cancels in softmax)
__global__ __launch_bounds__(256) void k_scan3(const unsigned short* __restrict__ vb,
                                               const float* __restrict__ base,
                                               unsigned short* __restrict__ gene,
                                               const unsigned int* __restrict__ mm) {
    int g = blockIdx.x * 4 + (threadIdx.x >> 6);
    int d = threadIdx.x & 63;
    int bh = g >> 6, c = g & 63;
    int b = bh >> 4;
    float vmin = fdec(mm[b * 2]), vmax = fdec(mm[b * 2 + 1]);
    float ir = __fdividef(1.0f, vmax - vmin + 1e-8f);
    const unsigned short* src = vb + (size_t)bh * S_ * 64 + (size_t)c * 32 * 64 + d;
    unsigned short* dst = gene + (size_t)bh * S_ * 64 + (size_t)c * 32 * 64 + d;
    float acc = base[(size_t)g * 64 + d];
#pragma unroll 4
    for (int i = 0; i < 32; ++i) {
        int s = c * 32 + i;
        acc += bf2f(src[(size_t)i * 64]);
        float phi = __fdividef(acc, (float)(s + 1));
        float inv = __fdividef(1.0f, (phi - vmin) * ir + 0.5f);
        float rs = inv;
#pragma unroll
        for (int m = 1; m < 64; m <<= 1) rs += __shfl_xor(rs, m);
        dst[(size_t)i * 64] = f2bf(__fdividef(inv, rs) * ir);
    }
}

// Fixed-max flash attention, block-cooperative staged tiles.
// Block = 4 waves covering 64 consecutive query rows of one bh; key tile = 64.
// v-tile + vt-tile double-buffered in padded LDS (reg-staged: issue-early / write-late).
// p = exp(s - (vmin*ir + 1)) in [~e^-2, ~e^0.1]: fixed shift, plain sums, one reduce at end.
__global__ __launch_bounds__(256, 3) void k_attn(const unsigned short* __restrict__ gene,
                                                 const unsigned short* __restrict__ vb,
                                                 const unsigned short* __restrict__ vt,
                                                 unsigned short* __restrict__ attn_out,
                                                 const unsigned int* __restrict__ mm) {
    __shared__ __align__(16) unsigned short v_lds[2][64][72];  // [buf][j-local][d] (+pad)
    __shared__ __align__(16) unsigned short t_lds[2][64][72];  // [buf][d][j-local] (+pad)
    __shared__ __align__(16) unsigned short plds[4][16 * 72];  // per-wave P tile
    int tid = threadIdx.x;
    int w = tid >> 6, lane = tid & 63;
    // XCD-aware decode: each XCD owns 4 bh; qt reversed (long blocks first)
    int bid = blockIdx.x;
    int xcd = bid & 7, slot = bid >> 3;
    int bh = xcd * 4 + (slot >> 5);
    int qt = 31 - (slot & 31);
    int i0 = qt * 64 + w * 16;
    int lrow = lane & 15, lgrp = lane >> 4;

    int b = bh >> 4;
    float vmin = fdec(mm[b * 2]), vmax = fdec(mm[b * 2 + 1]);
    float ir = __fdividef(1.0f, vmax - vmin + 1e-8f);
    float C = vmin * ir + 1.0f;  // fixed softmax shift

    const unsigned short* gbase = gene + (size_t)bh * S_ * 64;
    const unsigned short* vbase = vb + (size_t)bh * S_ * 64;
    const unsigned short* tbase = vt + (size_t)bh * 64 * S_;

    // per-thread staging pointers (64 rows x 4 col-chunks of 16 shorts)
    int srow = tid >> 2, scol = (tid & 3) * 16;
    const unsigned short* vstage = vbase + (size_t)srow * 64 + scol;   // advance j0*64 per tile
    const unsigned short* tstage = tbase + (size_t)srow * S_ + scol;   // advance j0 per tile

    bf16x8 ga0 = *(const bf16x8*)(gbase + (size_t)(i0 + lrow) * 64 + lgrp * 8);
    bf16x8 ga1 = *(const bf16x8*)(gbase + (size_t)(i0 + lrow) * 64 + 32 + lgrp * 8);

    f32x4 acc[4];
#pragma unroll
    for (int n = 0; n < 4; ++n) acc[n] = (f32x4){0.f, 0.f, 0.f, 0.f};
    float lsum[4] = {0.f, 0.f, 0.f, 0.f};
    unsigned short* pl = &plds[w][0];
    int njt = qt + 1;

    // prologue: stage tile 0 into buffer 0
    {
        uint4 a0 = *(const uint4*)(vstage);
        uint4 a1 = *(const uint4*)(vstage + 8);
        uint4 b0 = *(const uint4*)(tstage);
        uint4 b1 = *(const uint4*)(tstage + 8);
        *(uint4*)&v_lds[0][srow][scol] = a0;
        *(uint4*)&v_lds[0][srow][scol + 8] = a1;
        *(uint4*)&t_lds[0][srow][scol] = b0;
        *(uint4*)&t_lds[0][srow][scol + 8] = b1;
    }
    __syncthreads();

    for (int jt = 0; jt < njt; ++jt) {
        int cur = jt & 1;
        bool pf = (jt + 1 < njt);
        uint4 pa_, pb_, pc_, pd_;
        if (pf) {  // issue next-tile loads early; write after barrier (latency hides under compute)
            const unsigned short* vs = vstage + (size_t)(jt + 1) * 4096;
            const unsigned short* ts = tstage + (size_t)(jt + 1) * 64;
            pa_ = *(const uint4*)(vs);
            pb_ = *(const uint4*)(vs + 8);
            pc_ = *(const uint4*)(ts);
            pd_ = *(const uint4*)(ts + 8);
        }
        int j0 = jt << 6;
        // ---- scores: 16 queries x 64 keys ----
        f32x4 Sv[4];
#pragma unroll
        for (int n = 0; n < 4; ++n) {
            const unsigned short* vr = &v_lds[cur][n * 16 + lrow][lgrp * 8];
            bf16x8 b0 = *(const bf16x8*)(vr);
            bf16x8 b1 = *(const bf16x8*)(vr + 32);
            f32x4 c = (f32x4){0.f, 0.f, 0.f, 0.f};
            c = mfma16(ga0, b0, c);
            c = mfma16(ga1, b1, c);
            Sv[n] = c;
        }
        bool tail = (jt == qt);
#pragma unroll
        for (int n = 0; n < 4; ++n)
#pragma unroll
            for (int r = 0; r < 4; ++r) {
                float p = __expf(Sv[n][r] - C);
                if (tail) {
                    int ii = i0 + lgrp * 4 + r;
                    int jj = j0 + n * 16 + lrow;
                    p = (jj <= ii) ? p : 0.f;
                }
                lsum[r] += p;
                pl[(lgrp * 4 + r) * 72 + n * 16 + lrow] =
                    (unsigned short)((__float_as_uint(p) + 0x8000u) >> 16);
            }
        // wave-local LDS RAW: DS ops in-order per wave; compiler inserts lgkmcnt.
        bf16x8 pa0 = *(const bf16x8*)(pl + lrow * 72 + lgrp * 8);
        bf16x8 pa1 = *(const bf16x8*)(pl + lrow * 72 + 32 + lgrp * 8);
        // ---- PV: acc[n] += P(16x64) * vt(64 d x 64 keys) ----
#pragma unroll
        for (int n = 0; n < 4; ++n) {
            const unsigned short* tr = &t_lds[cur][n * 16 + lrow][lgrp * 8];
            bf16x8 t0 = *(const bf16x8*)(tr);
            bf16x8 t1 = *(const bf16x8*)(tr + 32);
            acc[n] = mfma16(pa0, t0, acc[n]);
            acc[n] = mfma16(pa1, t1, acc[n]);
        }
        __syncthreads();
        if (pf) {
            int nb = cur ^ 1;
            *(uint4*)&v_lds[nb][srow][scol] = pa_;
            *(uint4*)&v_lds[nb][srow][scol + 8] = pb_;
            *(uint4*)&t_lds[nb][srow][scol] = pc_;
            *(uint4*)&t_lds[nb][srow][scol + 8] = pd_;
        }
        __syncthreads();
    }
    // one-time denominator reduce across the 16 key-lanes (preserves lgrp row groups)
#pragma unroll
    for (int r = 0; r < 4; ++r) {
#pragma unroll
        for (int m = 1; m < 16; m <<= 1) lsum[r] += __shfl_xor(lsum[r], m);
        lsum[r] = __fdividef(1.0f, lsum[r]);
    }
    int bb = bh >> 4, h = bh & 15;
#pragma unroll
    for (int n = 0; n < 4; ++n)
#pragma unroll
        for (int r = 0; r < 4; ++r) {
            int ii = i0 + lgrp * 4 + r;
            int e = h * 64 + n * 16 + lrow;
            attn_out[(size_t)(bb * S_ + ii) * E_ + e] = f2bf(acc[n][r] * lsum[r]);
        }
}

extern "C" void kernel_launch(void* const* d_in, const int* in_sizes, int n_in,
                              void* d_out, int out_size, void* d_ws, size_t ws_size,
                              hipStream_t stream) {
    const float* x = (const float*)d_in[0];
    const float* wv_w = (const float*)d_in[1];
    const float* wv_b = (const float*)d_in[2];
    const float* wo_w = (const float*)d_in[3];
    const float* wo_b = (const float*)d_in[4];
    float* out = (float*)d_out;

    char* w = (char*)d_ws;
    unsigned short* x_bf = (unsigned short*)(w);               // 8 MB
    unsigned short* wv_bf = (unsigned short*)(w + 8388608);    // 2 MB
    unsigned short* wo_bf = (unsigned short*)(w + 10485760);   // 2 MB
    unsigned short* v_bf = (unsigned short*)(w + 12582912);    // 8 MB  [b][h][s][d]
    unsigned short* vt_bf = (unsigned short*)(w + 20971520);   // 8 MB  [b][h][d][s]
    float* ps = (float*)(w + 29360128);                        // 512 KB [bh][c][d]
    float* base = (float*)(w + 29884416);                      // 512 KB [bh][c][d]
    unsigned short* gene = (unsigned short*)(w + 46137344);    // 8 MB
    unsigned short* a_bf = (unsigned short*)(w + 54525952);    // 8 MB  [b][s][e]
    unsigned int* mm = (unsigned int*)(w + 62914560);          // 16 B
    if (ws_size < 62914576) return;  // insufficient workspace -> fail loudly

    k_init<<<1, 64, 0, stream>>>(mm);
    k_cast<<<2048, 256, 0, stream>>>(x, x_bf, 524288);
    k_cast<<<512, 256, 0, stream>>>(wv_w, wv_bf, 131072);
    k_cast<<<512, 256, 0, stream>>>(wo_w, wo_bf, 131072);
    k_gemm<0><<<dim3(32, 16), 256, 0, stream>>>(x_bf, wv_bf, wv_b, v_bf, nullptr, mm);
    k_transpose<<<dim3(32, 32), 256, 0, stream>>>(v_bf, vt_bf);
    k_scan1<<<512, 256, 0, stream>>>(v_bf, ps);
    k_scan2<<<32, 64, 0, stream>>>(ps, base);
    k_scan3<<<512, 256, 0, stream>>>(v_bf, base, gene, mm);
    k_attn<<<1024, 256, 0, stream>>>(gene, v_bf, vt_bf, a_bf, mm);
    k_gemm<1><<<dim3(32, 16), 256, 0, stream>>>(a_bf, wo_bf, wo_b, nullptr, out, nullptr);
}

// Round 6
// 154.740 us; speedup vs baseline: 3.4312x; 1.1472x over previous
//
#include <hip/hip_runtime.h>
#include <hip/hip_bf16.h>

#define B_ 2
#define S_ 2048
#define E_ 1024
#define H_ 16
#define D_ 64
#define M_ 4096  // B_*S_

typedef __bf16 bf16_t;
typedef bf16_t bf16x8 __attribute__((ext_vector_type(8)));
typedef float f32x4 __attribute__((ext_vector_type(4)));
typedef unsigned int u32;

__device__ __forceinline__ f32x4 mfma16(bf16x8 a, bf16x8 b, f32x4 c) {
    return __builtin_amdgcn_mfma_f32_16x16x32_bf16(a, b, c, 0, 0, 0);
}
__device__ __forceinline__ unsigned short f2bf(float f) {
    unsigned int u = __float_as_uint(f);
    unsigned int r = (u + 0x7fffu + ((u >> 16) & 1u)) >> 16;
    return (unsigned short)r;
}
__device__ __forceinline__ float bf2f(unsigned short s) {
    return __uint_as_float(((unsigned int)s) << 16);
}
// order-preserving float<->uint for atomic min/max
__device__ __forceinline__ unsigned int fenc(float x) {
    unsigned int u = __float_as_uint(x);
    return (u & 0x80000000u) ? ~u : (u | 0x80000000u);
}
__device__ __forceinline__ float fdec(unsigned int u) {
    return __uint_as_float((u & 0x80000000u) ? (u ^ 0x80000000u) : ~u);
}
// async global->LDS DMA, 16B per lane; LDS dest = wave-uniform base + lane*16
__device__ __forceinline__ void gload16(const void* g, void* l) {
    __builtin_amdgcn_global_load_lds((const __attribute__((address_space(1))) u32*)g,
                                     (__attribute__((address_space(3))) u32*)l, 16, 0, 0);
}

__global__ void k_init(unsigned int* mm) {
    int t = threadIdx.x;
    if (t < 2) { mm[t * 2] = 0xFFFFFFFFu; mm[t * 2 + 1] = 0u; }
}

__global__ __launch_bounds__(256) void k_cast(const float* __restrict__ src,
                                              unsigned short* __restrict__ dst, int n8) {
    int i = blockIdx.x * 256 + threadIdx.x;
    if (i >= n8) return;
    const float4* s4 = (const float4*)src;
    float4 a = s4[2 * i], c = s4[2 * i + 1];
    uint4 o;
    o.x = (unsigned int)f2bf(a.x) | ((unsigned int)f2bf(a.y) << 16);
    o.y = (unsigned int)f2bf(a.z) | ((unsigned int)f2bf(a.w) << 16);
    o.z = (unsigned int)f2bf(c.x) | ((unsigned int)f2bf(c.y) << 16);
    o.w = (unsigned int)f2bf(c.z) | ((unsigned int)f2bf(c.w) << 16);
    ((uint4*)dst)[i] = o;
}

// C[m][n] = sum_k A[m][k]*B[n][k] + bias[n].  A:[4096][1024], B:[1024][1024] (row=n, contiguous k), bf16.
// 128x128 tile, 4 waves (64x64 each), BK=64, global_load_lds(16B) double-buffered, counted
// vmcnt(8) pipeline (T3/T4 minimum form): loads stay in flight across raw s_barriers; never
// drain to 0 in the main loop. Swizzle: pre-swizzled GLOBAL source (chunk ^= row&7), same XOR
// on ds_read; LDS writes linear (both-sides-or-neither rule).
// MODE 0: write bf16 v [b][h][s][d] + transposed vt [b][h][d][s] + per-batch min/max atomics.
// MODE 1: write fp32 outf[m][n].
template <int MODE>
__global__ __launch_bounds__(256, 2) void k_gemm(const unsigned short* __restrict__ A,
                                                 const unsigned short* __restrict__ Bm,
                                                 const float* __restrict__ bias,
                                                 unsigned short* __restrict__ outb,
                                                 unsigned short* __restrict__ vtb,
                                                 float* __restrict__ outf,
                                                 unsigned int* __restrict__ mm) {
    __shared__ __align__(16) unsigned short Asm[2][8192];  // [buf][128 rows x 64 shorts]
    __shared__ __align__(16) unsigned short Bsm[2][8192];  // [buf][128 rows x 64 shorts]
    const int K = 1024;
    int tid = threadIdx.x, lane = tid & 63, wv = tid >> 6;
    int wm = wv >> 1, wn = wv & 1;
    int m0 = blockIdx.x * 128, n0 = blockIdx.y * 128;
    int lrow = lane & 15, lgrp = lane >> 4, sw = lane & 7;
    int r8 = lane >> 3, ch = lane & 7;
    // pre-swizzled global sources: lane covers (row = i*32 + wv*8 + r8, 16B chunk = ch ^ r8)
    const unsigned short* Ag = A + (size_t)(m0 + wv * 8 + r8) * K + ((ch ^ r8) << 3);
    const unsigned short* Bg = Bm + (size_t)(n0 + wv * 8 + r8) * K + ((ch ^ r8) << 3);

#define STAGE(buf, kk)                                                                     \
    {                                                                                      \
        _Pragma("unroll") for (int i = 0; i < 4; ++i)                                      \
            gload16(Ag + (size_t)(i * 32) * K + (kk), &Asm[buf][(i * 32 + wv * 8) * 64]);  \
        _Pragma("unroll") for (int i = 0; i < 4; ++i)                                      \
            gload16(Bg + (size_t)(i * 32) * K + (kk), &Bsm[buf][(i * 32 + wv * 8) * 64]);  \
    }
#define COMPUTE(buf)                                                                        \
    {                                                                                       \
        _Pragma("unroll") for (int kh = 0; kh < 2; ++kh) {                                  \
            int cp = (((kh << 2) | lgrp) ^ sw) << 3;                                        \
            bf16x8 af[4], bfr[4];                                                           \
            _Pragma("unroll") for (int mt = 0; mt < 4; ++mt)                                \
                af[mt] = *(const bf16x8*)&Asm[buf][(wm * 64 + mt * 16 + lrow) * 64 + cp];   \
            _Pragma("unroll") for (int nt = 0; nt < 4; ++nt)                                \
                bfr[nt] = *(const bf16x8*)&Bsm[buf][(wn * 64 + nt * 16 + lrow) * 64 + cp];  \
            _Pragma("unroll") for (int mt = 0; mt < 4; ++mt)                                \
                _Pragma("unroll") for (int nt = 0; nt < 4; ++nt)                            \
                    acc[mt][nt] = mfma16(af[mt], bfr[nt], acc[mt][nt]);                     \
        }                                                                                   \
    }

    f32x4 acc[4][4];
#pragma unroll
    for (int i = 0; i < 4; ++i)
#pragma unroll
        for (int j = 0; j < 4; ++j) acc[i][j] = (f32x4){0.f, 0.f, 0.f, 0.f};

    STAGE(0, 0);
    STAGE(1, 64);
    for (int t = 0; t < 15; ++t) {
        asm volatile("s_waitcnt vmcnt(8)" ::: "memory");  // buf[t&1] landed; t+1's 8 stay in flight
        __builtin_amdgcn_s_barrier();
        __builtin_amdgcn_sched_barrier(0);
        COMPUTE(t & 1);
        asm volatile("s_waitcnt lgkmcnt(0)" ::: "memory");  // my reads done before overwrite
        __builtin_amdgcn_s_barrier();
        __builtin_amdgcn_sched_barrier(0);
        if (t < 14) STAGE(t & 1, (t + 2) * 64);
    }
    asm volatile("s_waitcnt vmcnt(0)" ::: "memory");
    __builtin_amdgcn_s_barrier();
    __builtin_amdgcn_sched_barrier(0);
    COMPUTE(1);
#undef STAGE
#undef COMPUTE

    float vmin = 1e30f, vmax = -1e30f;
#pragma unroll
    for (int nt = 0; nt < 4; ++nt) {
        int ncol = n0 + wn * 64 + nt * 16 + lrow;
        float bs = bias[ncol];
#pragma unroll
        for (int mt = 0; mt < 4; ++mt) {
            unsigned int lo = 0, hi = 0;
#pragma unroll
            for (int r = 0; r < 4; ++r) {
                int mrow = m0 + wm * 64 + mt * 16 + lgrp * 4 + r;
                float val = acc[mt][nt][r] + bs;
                if constexpr (MODE == 0) {
                    vmin = fminf(vmin, val);
                    vmax = fmaxf(vmax, val);
                    int b = mrow >> 11, s = mrow & 2047, h = ncol >> 6, d = ncol & 63;
                    unsigned short bfv = f2bf(val);
                    outb[(size_t)((b * 16 + h) * 2048 + s) * 64 + d] = bfv;
                    if (r < 2) lo |= ((unsigned int)bfv) << (16 * r);
                    else       hi |= ((unsigned int)bfv) << (16 * (r - 2));
                } else {
                    outf[(size_t)mrow * 1024 + ncol] = val;
                }
            }
            if constexpr (MODE == 0) {  // fused transpose write: 4 consecutive s at fixed d
                int mrow0 = m0 + wm * 64 + mt * 16 + lgrp * 4;
                int b = mrow0 >> 11, s0 = mrow0 & 2047;
                int h = ncol >> 6, d = ncol & 63;
                uint2 pk; pk.x = lo; pk.y = hi;
                *(uint2*)&vtb[((size_t)(b * 16 + h) * 64 + d) * 2048 + s0] = pk;
            }
        }
    }
    if constexpr (MODE == 0) {
#pragma unroll
        for (int m = 1; m < 64; m <<= 1) {
            vmin = fminf(vmin, __shfl_xor(vmin, m));
            vmax = fmaxf(vmax, __shfl_xor(vmax, m));
        }
        if (lane == 0) {
            int b = m0 >> 11;
            atomicMin(&mm[b * 2], fenc(vmin));
            atomicMax(&mm[b * 2 + 1], fenc(vmax));
        }
    }
}

// ---- hierarchical prefix scan over s (2048 chains of length 2048) ----
// pass 1: one wave per (bh, 32-row chunk); lane=d sums its 32 values -> ps[bh][c][d]
__global__ __launch_bounds__(256) void k_scan1(const unsigned short* __restrict__ vb,
                                               float* __restrict__ ps) {
    int g = blockIdx.x * 4 + (threadIdx.x >> 6);
    int d = threadIdx.x & 63;
    int bh = g >> 6, c = g & 63;
    const unsigned short* src = vb + (size_t)bh * S_ * 64 + (size_t)c * 32 * 64 + d;
    float a0 = 0.f, a1 = 0.f, a2 = 0.f, a3 = 0.f;
#pragma unroll
    for (int i = 0; i < 32; i += 4) {
        a0 += bf2f(src[(size_t)i * 64]);
        a1 += bf2f(src[(size_t)(i + 1) * 64]);
        a2 += bf2f(src[(size_t)(i + 2) * 64]);
        a3 += bf2f(src[(size_t)(i + 3) * 64]);
    }
    ps[(size_t)g * 64 + d] = (a0 + a1) + (a2 + a3);
}

// pass 2: one thread per (bh,d); register scan of 64 chunk sums -> exclusive base[bh][c][d]
__global__ __launch_bounds__(64) void k_scan2(const float* __restrict__ ps,
                                              float* __restrict__ base) {
    int bh = blockIdx.x;
    int d = threadIdx.x;
    const float* p = ps + (size_t)bh * 64 * 64 + d;
    float* bo = base + (size_t)bh * 64 * 64 + d;
    float vals[64];
#pragma unroll
    for (int c = 0; c < 64; ++c) vals[c] = p[(size_t)c * 64];
    float run = 0.f;
#pragma unroll
    for (int c = 0; c < 64; ++c) {
        float t = vals[c];
        vals[c] = run;
        run += t;
    }
#pragma unroll
    for (int c = 0; c < 64; ++c) bo[(size_t)c * 64] = vals[c];
}

// pass 3: one wave per (bh, chunk); resume scan from base, fuse rowsum -> gene directly.
// gene = inv / rowsum(inv) * ir  (inv_range folded in; min-shift cancels in softmax)
__global__ __launch_bounds__(256) void k_scan3(const unsigned short* __restrict__ vb,
                                               const float* __restrict__ base,
                                               unsigned short* __restrict__ gene,
                                               const unsigned int* __restrict__ mm) {
    int g = blockIdx.x * 4 + (threadIdx.x >> 6);
    int d = threadIdx.x & 63;
    int bh = g >> 6, c = g & 63;
    int b = bh >> 4;
    float vmin = fdec(mm[b * 2]), vmax = fdec(mm[b * 2 + 1]);
    float ir = __fdividef(1.0f, vmax - vmin + 1e-8f);
    const unsigned short* src = vb + (size_t)bh * S_ * 64 + (size_t)c * 32 * 64 + d;
    unsigned short* dst = gene + (size_t)bh * S_ * 64 + (size_t)c * 32 * 64 + d;
    float acc = base[(size_t)g * 64 + d];
#pragma unroll 4
    for (int i = 0; i < 32; ++i) {
        int s = c * 32 + i;
        acc += bf2f(src[(size_t)i * 64]);
        float phi = __fdividef(acc, (float)(s + 1));
        float inv = __fdividef(1.0f, (phi - vmin) * ir + 0.5f);
        float rs = inv;
#pragma unroll
        for (int m = 1; m < 64; m <<= 1) rs += __shfl_xor(rs, m);
        dst[(size_t)i * 64] = f2bf(__fdividef(inv, rs) * ir);
    }
}

// Fixed-max flash attention, block-cooperative staged tiles.
// Block = 4 waves covering 64 consecutive query rows of one bh; key tile = 64.
// v-tile + vt-tile double-buffered in padded LDS (reg-staged: issue-early / write-late).
// p = exp(s - (vmin*ir + 1)) in [~e^-2, ~e^0.1]: fixed shift, plain sums, one reduce at end.
__global__ __launch_bounds__(256, 3) void k_attn(const unsigned short* __restrict__ gene,
                                                 const unsigned short* __restrict__ vb,
                                                 const unsigned short* __restrict__ vt,
                                                 unsigned short* __restrict__ attn_out,
                                                 const unsigned int* __restrict__ mm) {
    __shared__ __align__(16) unsigned short v_lds[2][64][72];  // [buf][j-local][d] (+pad)
    __shared__ __align__(16) unsigned short t_lds[2][64][72];  // [buf][d][j-local] (+pad)
    __shared__ __align__(16) unsigned short plds[4][16 * 72];  // per-wave P tile
    int tid = threadIdx.x;
    int w = tid >> 6, lane = tid & 63;
    // XCD-aware decode: each XCD owns 4 bh; qt reversed (long blocks first)
    int bid = blockIdx.x;
    int xcd = bid & 7, slot = bid >> 3;
    int bh = xcd * 4 + (slot >> 5);
    int qt = 31 - (slot & 31);
    int i0 = qt * 64 + w * 16;
    int lrow = lane & 15, lgrp = lane >> 4;

    int b = bh >> 4;
    float vmin = fdec(mm[b * 2]), vmax = fdec(mm[b * 2 + 1]);
    float ir = __fdividef(1.0f, vmax - vmin + 1e-8f);
    float C = vmin * ir + 1.0f;  // fixed softmax shift

    const unsigned short* gbase = gene + (size_t)bh * S_ * 64;
    const unsigned short* vbase = vb + (size_t)bh * S_ * 64;
    const unsigned short* tbase = vt + (size_t)bh * 64 * S_;

    // per-thread staging pointers (64 rows x 4 col-chunks of 16 shorts)
    int srow = tid >> 2, scol = (tid & 3) * 16;
    const unsigned short* vstage = vbase + (size_t)srow * 64 + scol;   // advance j0*64 per tile
    const unsigned short* tstage = tbase + (size_t)srow * S_ + scol;   // advance j0 per tile

    bf16x8 ga0 = *(const bf16x8*)(gbase + (size_t)(i0 + lrow) * 64 + lgrp * 8);
    bf16x8 ga1 = *(const bf16x8*)(gbase + (size_t)(i0 + lrow) * 64 + 32 + lgrp * 8);

    f32x4 acc[4];
#pragma unroll
    for (int n = 0; n < 4; ++n) acc[n] = (f32x4){0.f, 0.f, 0.f, 0.f};
    float lsum[4] = {0.f, 0.f, 0.f, 0.f};
    unsigned short* pl = &plds[w][0];
    int njt = qt + 1;

    // prologue: stage tile 0 into buffer 0
    {
        uint4 a0 = *(const uint4*)(vstage);
        uint4 a1 = *(const uint4*)(vstage + 8);
        uint4 b0 = *(const uint4*)(tstage);
        uint4 b1 = *(const uint4*)(tstage + 8);
        *(uint4*)&v_lds[0][srow][scol] = a0;
        *(uint4*)&v_lds[0][srow][scol + 8] = a1;
        *(uint4*)&t_lds[0][srow][scol] = b0;
        *(uint4*)&t_lds[0][srow][scol + 8] = b1;
    }
    __syncthreads();

    for (int jt = 0; jt < njt; ++jt) {
        int cur = jt & 1;
        bool pf = (jt + 1 < njt);
        uint4 pa_, pb_, pc_, pd_;
        if (pf) {  // issue next-tile loads early; write after barrier (latency hides under compute)
            const unsigned short* vs = vstage + (size_t)(jt + 1) * 4096;
            const unsigned short* ts = tstage + (size_t)(jt + 1) * 64;
            pa_ = *(const uint4*)(vs);
            pb_ = *(const uint4*)(vs + 8);
            pc_ = *(const uint4*)(ts);
            pd_ = *(const uint4*)(ts + 8);
        }
        int j0 = jt << 6;
        // ---- scores: 16 queries x 64 keys ----
        f32x4 Sv[4];
#pragma unroll
        for (int n = 0; n < 4; ++n) {
            const unsigned short* vr = &v_lds[cur][n * 16 + lrow][lgrp * 8];
            bf16x8 b0 = *(const bf16x8*)(vr);
            bf16x8 b1 = *(const bf16x8*)(vr + 32);
            f32x4 c = (f32x4){0.f, 0.f, 0.f, 0.f};
            c = mfma16(ga0, b0, c);
            c = mfma16(ga1, b1, c);
            Sv[n] = c;
        }
        bool tail = (jt == qt);
#pragma unroll
        for (int n = 0; n < 4; ++n)
#pragma unroll
            for (int r = 0; r < 4; ++r) {
                float p = __expf(Sv[n][r] - C);
                if (tail) {
                    int ii = i0 + lgrp * 4 + r;
                    int jj = j0 + n * 16 + lrow;
                    p = (jj <= ii) ? p : 0.f;
                }
                lsum[r] += p;
                pl[(lgrp * 4 + r) * 72 + n * 16 + lrow] =
                    (unsigned short)((__float_as_uint(p) + 0x8000u) >> 16);
            }
        // wave-local LDS RAW: DS ops in-order per wave; compiler inserts lgkmcnt.
        bf16x8 pa0 = *(const bf16x8*)(pl + lrow * 72 + lgrp * 8);
        bf16x8 pa1 = *(const bf16x8*)(pl + lrow * 72 + 32 + lgrp * 8);
        // ---- PV: acc[n] += P(16x64) * vt(64 d x 64 keys) ----
#pragma unroll
        for (int n = 0; n < 4; ++n) {
            const unsigned short* tr = &t_lds[cur][n * 16 + lrow][lgrp * 8];
            bf16x8 t0 = *(const bf16x8*)(tr);
            bf16x8 t1 = *(const bf16x8*)(tr + 32);
            acc[n] = mfma16(pa0, t0, acc[n]);
            acc[n] = mfma16(pa1, t1, acc[n]);
        }
        __syncthreads();
        if (pf) {
            int nb = cur ^ 1;
            *(uint4*)&v_lds[nb][srow][scol] = pa_;
            *(uint4*)&v_lds[nb][srow][scol + 8] = pb_;
            *(uint4*)&t_lds[nb][srow][scol] = pc_;
            *(uint4*)&t_lds[nb][srow][scol + 8] = pd_;
        }
        __syncthreads();
    }
    // one-time denominator reduce across the 16 key-lanes (preserves lgrp row groups)
#pragma unroll
    for (int r = 0; r < 4; ++r) {
#pragma unroll
        for (int m = 1; m < 16; m <<= 1) lsum[r] += __shfl_xor(lsum[r], m);
        lsum[r] = __fdividef(1.0f, lsum[r]);
    }
    int bb = bh >> 4, h = bh & 15;
#pragma unroll
    for (int n = 0; n < 4; ++n)
#pragma unroll
        for (int r = 0; r < 4; ++r) {
            int ii = i0 + lgrp * 4 + r;
            int e = h * 64 + n * 16 + lrow;
            attn_out[(size_t)(bb * S_ + ii) * E_ + e] = f2bf(acc[n][r] * lsum[r]);
        }
}

extern "C" void kernel_launch(void* const* d_in, const int* in_sizes, int n_in,
                              void* d_out, int out_size, void* d_ws, size_t ws_size,
                              hipStream_t stream) {
    const float* x = (const float*)d_in[0];
    const float* wv_w = (const float*)d_in[1];
    const float* wv_b = (const float*)d_in[2];
    const float* wo_w = (const float*)d_in[3];
    const float* wo_b = (const float*)d_in[4];
    float* out = (float*)d_out;

    char* w = (char*)d_ws;
    unsigned short* x_bf = (unsigned short*)(w);               // 8 MB
    unsigned short* wv_bf = (unsigned short*)(w + 8388608);    // 2 MB
    unsigned short* wo_bf = (unsigned short*)(w + 10485760);   // 2 MB
    unsigned short* v_bf = (unsigned short*)(w + 12582912);    // 8 MB  [b][h][s][d]
    unsigned short* vt_bf = (unsigned short*)(w + 20971520);   // 8 MB  [b][h][d][s]
    float* ps = (float*)(w + 29360128);                        // 512 KB [bh][c][d]
    float* base = (float*)(w + 29884416);                      // 512 KB [bh][c][d]
    unsigned short* gene = (unsigned short*)(w + 46137344);    // 8 MB
    unsigned short* a_bf = (unsigned short*)(w + 54525952);    // 8 MB  [b][s][e]
    unsigned int* mm = (unsigned int*)(w + 62914560);          // 16 B
    if (ws_size < 62914576) return;  // insufficient workspace -> fail loudly

    k_init<<<1, 64, 0, stream>>>(mm);
    k_cast<<<2048, 256, 0, stream>>>(x, x_bf, 524288);
    k_cast<<<512, 256, 0, stream>>>(wv_w, wv_bf, 131072);
    k_cast<<<512, 256, 0, stream>>>(wo_w, wo_bf, 131072);
    k_gemm<0><<<dim3(32, 8), 256, 0, stream>>>(x_bf, wv_bf, wv_b, v_bf, vt_bf, nullptr, mm);
    k_scan1<<<512, 256, 0, stream>>>(v_bf, ps);
    k_scan2<<<32, 64, 0, stream>>>(ps, base);
    k_scan3<<<512, 256, 0, stream>>>(v_bf, base, gene, mm);
    k_attn<<<1024, 256, 0, stream>>>(gene, v_bf, vt_bf, a_bf, mm);
    k_gemm<1><<<dim3(32, 8), 256, 0, stream>>>(a_bf, wo_bf, wo_b, nullptr, nullptr, out, nullptr);
}